// Round 1
// baseline (6954.868 us; speedup 1.0000x reference)
//
#include <hip/hip_runtime.h>
#include <math.h>

#define VEN_  30000
#define Dd    620
#define Hh    1000
#define Gg    4000   // 4*H
#define Mm    1000
#define Bb    32
#define Ss    20
#define Tt    20
#define LTILES 469   // ceil(30000/64)

__device__ __forceinline__ float sigf(float x) { return 1.0f / (1.0f + __expf(-x)); }
__device__ __forceinline__ float dot4(float4 a, float4 b) {
    return a.x * b.x + a.y * b.y + a.z * b.z + a.w * b.w;
}

// ---------------- embedding gather (float4, rows of 620 = 155 float4) -------
__global__ void gather_emb(const float4* __restrict__ emb, const int* __restrict__ toks,
                           int tstride, float4* __restrict__ out) {
    int i = blockIdx.x * blockDim.x + threadIdx.x;   // over 640*155
    if (i >= Bb * Tt * 155) return;
    int row = i / 155, d4 = i % 155;
    int b = row / Tt, t = row % Tt;
    int tok = toks[b * tstride + t];
    out[row * 155 + d4] = emb[tok * 155 + d4];
}

// ---------------- generic tiled GEMM: C[M,N] = A[M,K] * B[N,K]^T (+bias) ----
// MODE 0: write C (beta ? C += : C =), with per-col bias
// MODE 1: logits stats epilogue: per-(row, 64-col tile) max & sumexp partials
#define FMA16(a, b)                                                                         \
    acc[0][0] += a.x * b.x; acc[0][1] += a.x * b.y; acc[0][2] += a.x * b.z; acc[0][3] += a.x * b.w; \
    acc[1][0] += a.y * b.x; acc[1][1] += a.y * b.y; acc[1][2] += a.y * b.z; acc[1][3] += a.y * b.w; \
    acc[2][0] += a.z * b.x; acc[2][1] += a.z * b.y; acc[2][2] += a.z * b.z; acc[2][3] += a.z * b.w; \
    acc[3][0] += a.w * b.x; acc[3][1] += a.w * b.y; acc[3][2] += a.w * b.z; acc[3][3] += a.w * b.w;

template <int MODE>
__global__ __launch_bounds__(256) void gemm64(
    const float* __restrict__ A, const float* __restrict__ B,
    const float* __restrict__ bias, float* __restrict__ C,
    float* __restrict__ pm, float* __restrict__ ps,
    int M, int N, int K, int beta)
{
    __shared__ float As[32][68];   // [k][m], pad 68 so float4 rows stay 16B-aligned
    __shared__ float Bs[32][68];   // [k][n]
    const int tid = threadIdx.x;
    const int tn = tid & 15;       // col quad
    const int tm = tid >> 4;       // row quad 0..15
    const int row0 = blockIdx.y * 64, col0 = blockIdx.x * 64;
    const int lr  = tid >> 2;      // 0..63
    const int lc0 = (tid & 3) * 8; // 0,8,16,24
    float acc[4][4] = {};

    for (int kk = 0; kk < K; kk += 32) {
        // ---- stage A tile (transposed into LDS)
        {
            int r = row0 + lr;
            bool kfull = (kk + lc0 + 7 < K);
            if (r < M && kfull) {
                float4 v0 = *(const float4*)&A[(size_t)r * K + kk + lc0];
                float4 v1 = *(const float4*)&A[(size_t)r * K + kk + lc0 + 4];
                As[lc0 + 0][lr] = v0.x; As[lc0 + 1][lr] = v0.y; As[lc0 + 2][lr] = v0.z; As[lc0 + 3][lr] = v0.w;
                As[lc0 + 4][lr] = v1.x; As[lc0 + 5][lr] = v1.y; As[lc0 + 6][lr] = v1.z; As[lc0 + 7][lr] = v1.w;
            } else {
                #pragma unroll
                for (int jj = 0; jj < 8; ++jj) {
                    int c = kk + lc0 + jj;
                    As[lc0 + jj][lr] = (r < M && c < K) ? A[(size_t)r * K + c] : 0.f;
                }
            }
            int rb = col0 + lr;
            if (rb < N && kfull) {
                float4 v0 = *(const float4*)&B[(size_t)rb * K + kk + lc0];
                float4 v1 = *(const float4*)&B[(size_t)rb * K + kk + lc0 + 4];
                Bs[lc0 + 0][lr] = v0.x; Bs[lc0 + 1][lr] = v0.y; Bs[lc0 + 2][lr] = v0.z; Bs[lc0 + 3][lr] = v0.w;
                Bs[lc0 + 4][lr] = v1.x; Bs[lc0 + 5][lr] = v1.y; Bs[lc0 + 6][lr] = v1.z; Bs[lc0 + 7][lr] = v1.w;
            } else {
                #pragma unroll
                for (int jj = 0; jj < 8; ++jj) {
                    int c = kk + lc0 + jj;
                    Bs[lc0 + jj][lr] = (rb < N && c < K) ? B[(size_t)rb * K + c] : 0.f;
                }
            }
        }
        __syncthreads();
        #pragma unroll
        for (int k2 = 0; k2 < 32; ++k2) {
            float4 a = *(const float4*)&As[k2][tm * 4];
            float4 b = *(const float4*)&Bs[k2][tn * 4];
            FMA16(a, b)
        }
        __syncthreads();
    }

    if (MODE == 0) {
        #pragma unroll
        for (int i = 0; i < 4; ++i) {
            int r = row0 + tm * 4 + i;
            if (r >= M) continue;
            #pragma unroll
            for (int jj = 0; jj < 4; ++jj) {
                int c = col0 + tn * 4 + jj;
                if (c >= N) continue;
                float v = acc[i][jj] + (bias ? bias[c] : 0.f);
                if (beta) v += C[(size_t)r * N + c];
                C[(size_t)r * N + c] = v;
            }
        }
    } else {
        // per-row stats over this 64-col tile, reduced across the 16 lanes of a tm-group
        #pragma unroll
        for (int i = 0; i < 4; ++i) {
            int r = row0 + tm * 4 + i;
            float vals[4];
            float vmax = -1e30f;
            #pragma unroll
            for (int jj = 0; jj < 4; ++jj) {
                int c = col0 + tn * 4 + jj;
                vals[jj] = (c < N) ? (acc[i][jj] + bias[c]) : -1e30f;
                vmax = fmaxf(vmax, vals[jj]);
            }
            #pragma unroll
            for (int off = 8; off; off >>= 1) vmax = fmaxf(vmax, __shfl_xor(vmax, off, 16));
            float se = 0.f;
            #pragma unroll
            for (int jj = 0; jj < 4; ++jj) {
                int c = col0 + tn * 4 + jj;
                if (c < N) se += __expf(vals[jj] - vmax);
            }
            #pragma unroll
            for (int off = 8; off; off >>= 1) se += __shfl_xor(se, off, 16);
            if (tn == 0 && r < M) {
                pm[(size_t)r * LTILES + blockIdx.x] = vmax;
                ps[(size_t)r * LTILES + blockIdx.x] = se;
            }
        }
    }
}

// ---------------- LSTM step: gates = xp[:,t,:] + h_prev @ Whh^T, fused update
// grid: (4 j-chunks of 256, 16 batch-pairs); each thread: 4 gates x 2 batches
__global__ __launch_bounds__(256) void lstm_step(
    const float* __restrict__ xp,    // [B, T, 4H] (bias already folded in)
    const float* __restrict__ Whh,   // [4H, H]
    float* __restrict__ c_buf,       // [B, H]
    float* __restrict__ hs,          // [B, T, H]
    int t)
{
    __shared__ __align__(16) float hprev[2 * Hh];
    const int b0 = blockIdx.y * 2;
    const int j = blockIdx.x * 256 + threadIdx.x;
    for (int idx = threadIdx.x; idx < 2 * Hh; idx += 256) {
        int bb = idx / Hh, hh = idx % Hh;
        hprev[idx] = (t == 0) ? 0.f : hs[((size_t)(b0 + bb) * Tt + (t - 1)) * Hh + hh];
    }
    __syncthreads();
    if (j >= Hh) return;

    float acc[2][4];
    #pragma unroll
    for (int bb = 0; bb < 2; ++bb) {
        const float* xpr = xp + ((size_t)(b0 + bb) * Tt + t) * Gg;
        acc[bb][0] = xpr[j];
        acc[bb][1] = xpr[Hh + j];
        acc[bb][2] = xpr[2 * Hh + j];
        acc[bb][3] = xpr[3 * Hh + j];
    }
    const float4* w0 = (const float4*)(Whh + (size_t)(0 * Hh + j) * Hh);
    const float4* w1 = (const float4*)(Whh + (size_t)(1 * Hh + j) * Hh);
    const float4* w2 = (const float4*)(Whh + (size_t)(2 * Hh + j) * Hh);
    const float4* w3 = (const float4*)(Whh + (size_t)(3 * Hh + j) * Hh);
    const float4* h0 = (const float4*)(hprev);
    const float4* h1 = (const float4*)(hprev + Hh);
    for (int h4 = 0; h4 < Hh / 4; ++h4) {
        float4 a0 = w0[h4], a1 = w1[h4], a2 = w2[h4], a3 = w3[h4];
        float4 v0 = h0[h4], v1 = h1[h4];
        acc[0][0] += dot4(a0, v0); acc[0][1] += dot4(a1, v0);
        acc[0][2] += dot4(a2, v0); acc[0][3] += dot4(a3, v0);
        acc[1][0] += dot4(a0, v1); acc[1][1] += dot4(a1, v1);
        acc[1][2] += dot4(a2, v1); acc[1][3] += dot4(a3, v1);
    }
    #pragma unroll
    for (int bb = 0; bb < 2; ++bb) {
        int b = b0 + bb;
        float c_old = c_buf[(size_t)b * Hh + j];
        float iv = sigf(acc[bb][0]), fv = sigf(acc[bb][1]);
        float gv = tanhf(acc[bb][2]), ov = sigf(acc[bb][3]);
        float cn = fv * c_old + iv * gv;
        float hn = ov * tanhf(cn);
        c_buf[(size_t)b * Hh + j] = cn;
        hs[((size_t)b * Tt + t) * Hh + j] = hn;
    }
}

// ---------------- attention scores: one wave per (b,s,t) --------------------
__global__ __launch_bounds__(256) void attn_scores(
    const float* __restrict__ Ua, const float* __restrict__ Wa,
    const float* __restrict__ Va_w, const float* __restrict__ Va_b,
    float* __restrict__ scores)
{
    int wave = (blockIdx.x * 256 + threadIdx.x) >> 6;
    int lane = threadIdx.x & 63;
    if (wave >= Bb * Ss * Tt) return;
    int b = wave / (Ss * Tt);
    int rem = wave % (Ss * Tt);
    int s = rem / Tt, t = rem % Tt;
    const float* ua = Ua + (size_t)(b * Ss + s) * Hh;
    const float* wa = Wa + (size_t)(b * Tt + t) * Hh;
    float acc = 0.f;
    for (int h = lane; h < Hh; h += 64)
        acc += tanhf(ua[h] + wa[h]) * Va_w[h];
    #pragma unroll
    for (int off = 32; off; off >>= 1) acc += __shfl_xor(acc, off, 64);
    if (lane == 0) scores[(size_t)(b * Ss + s) * Tt + t] = acc + Va_b[0];
}

// ---------------- softmax over s (20) + context --------------------------
__global__ __launch_bounds__(256) void softmax_context(
    const float* __restrict__ scores, const float* __restrict__ enc_h,
    float* __restrict__ context)
{
    __shared__ float w[Ss];
    int b = blockIdx.x / Tt, t = blockIdx.x % Tt;
    if (threadIdx.x == 0) {
        float sc[Ss];
        float mx = -1e30f;
        for (int s = 0; s < Ss; ++s) {
            sc[s] = scores[(size_t)(b * Ss + s) * Tt + t];
            mx = fmaxf(mx, sc[s]);
        }
        float sum = 0.f;
        for (int s = 0; s < Ss; ++s) { float e = __expf(sc[s] - mx); w[s] = e; sum += e; }
        float inv = 1.f / sum;
        for (int s = 0; s < Ss; ++s) w[s] *= inv;
    }
    __syncthreads();
    for (int h = threadIdx.x; h < Hh; h += 256) {
        float acc = 0.f;
        #pragma unroll
        for (int s = 0; s < Ss; ++s)
            acc += w[s] * enc_h[(size_t)(b * Ss + s) * Hh + h];
        context[(size_t)(b * Tt + t) * Hh + h] = acc;
    }
}

// ---------------- maxout over pairs ---------------------------------------
__global__ void maxout(const float* __restrict__ u, float* __restrict__ tmax) {
    int i = blockIdx.x * blockDim.x + threadIdx.x;
    if (i >= Bb * Tt * Mm) return;
    int row = i / Mm, m = i % Mm;
    tmax[i] = fmaxf(u[(size_t)row * 2 * Mm + 2 * m], u[(size_t)row * 2 * Mm + 2 * m + 1]);
}

// ---------------- per-row NLL from logsumexp partials ----------------------
__global__ __launch_bounds__(256) void nll_kernel(
    const float* __restrict__ pm, const float* __restrict__ ps,
    const float* __restrict__ tmax, const float* __restrict__ Ww,
    const float* __restrict__ Wb, const int* __restrict__ y,
    float* __restrict__ nll)
{
    __shared__ float sm[4];
    int row = blockIdx.x;
    int tid = threadIdx.x;
    // block max over tile maxima
    float mx = -1e30f;
    for (int i = tid; i < LTILES; i += 256) mx = fmaxf(mx, pm[(size_t)row * LTILES + i]);
    #pragma unroll
    for (int off = 32; off; off >>= 1) mx = fmaxf(mx, __shfl_xor(mx, off, 64));
    if ((tid & 63) == 0) sm[tid >> 6] = mx;
    __syncthreads();
    mx = fmaxf(fmaxf(sm[0], sm[1]), fmaxf(sm[2], sm[3]));
    __syncthreads();
    // combined sumexp
    float s = 0.f;
    for (int i = tid; i < LTILES; i += 256)
        s += ps[(size_t)row * LTILES + i] * __expf(pm[(size_t)row * LTILES + i] - mx);
    #pragma unroll
    for (int off = 32; off; off >>= 1) s += __shfl_xor(s, off, 64);
    if ((tid & 63) == 0) sm[tid >> 6] = s;
    __syncthreads();
    s = sm[0] + sm[1] + sm[2] + sm[3];
    __syncthreads();
    // label logit
    int b = row / Tt, t = row % Tt;
    int lab = y[b * (Tt + 1) + t + 1];
    float d = 0.f;
    for (int m = tid; m < Mm; m += 256)
        d += tmax[(size_t)row * Mm + m] * Ww[(size_t)lab * Mm + m];
    #pragma unroll
    for (int off = 32; off; off >>= 1) d += __shfl_xor(d, off, 64);
    if ((tid & 63) == 0) sm[tid >> 6] = d;
    __syncthreads();
    d = sm[0] + sm[1] + sm[2] + sm[3] + Wb[lab];
    if (tid == 0) nll[row] = (mx + logf(s)) - d;
}

// ---------------- final loss: sum(nll)/B -----------------------------------
__global__ void loss_kernel(const float* __restrict__ nll, float* __restrict__ out) {
    __shared__ float sm[4];
    float s = 0.f;
    for (int i = threadIdx.x; i < Bb * Tt; i += 256) s += nll[i];
    #pragma unroll
    for (int off = 32; off; off >>= 1) s += __shfl_xor(s, off, 64);
    if ((threadIdx.x & 63) == 0) sm[threadIdx.x >> 6] = s;
    __syncthreads();
    if (threadIdx.x == 0) out[0] = (sm[0] + sm[1] + sm[2] + sm[3]) / (float)Bb;
}

extern "C" void kernel_launch(void* const* d_in, const int* in_sizes, int n_in,
                              void* d_out, int out_size, void* d_ws, size_t ws_size,
                              hipStream_t stream)
{
    const int* x = (const int*)d_in[0];
    const int* y = (const int*)d_in[1];
    const float* emb_de  = (const float*)d_in[2];
    const float* emb_en  = (const float*)d_in[3];
    const float* enc_Wih = (const float*)d_in[4];
    const float* enc_Whh = (const float*)d_in[5];
    const float* enc_b   = (const float*)d_in[6];
    const float* dec_Wih = (const float*)d_in[7];
    const float* dec_Whh = (const float*)d_in[8];
    const float* dec_b   = (const float*)d_in[9];
    const float* Wa_w = (const float*)d_in[10];
    const float* Wa_b = (const float*)d_in[11];
    const float* Ua_w = (const float*)d_in[12];
    const float* Ua_b = (const float*)d_in[13];
    const float* Va_w = (const float*)d_in[14];
    const float* Va_b = (const float*)d_in[15];
    const float* U_w  = (const float*)d_in[16];
    const float* U_b  = (const float*)d_in[17];
    const float* V_w  = (const float*)d_in[18];
    const float* V_b  = (const float*)d_in[19];
    const float* C_w  = (const float*)d_in[20];
    const float* C_b  = (const float*)d_in[21];
    const float* W_w  = (const float*)d_in[22];
    const float* W_b  = (const float*)d_in[23];

    float* ws = (float*)d_ws;
    float* e_de_g  = ws;                       // 640*620
    float* e_en_g  = e_de_g + 640 * 620;       // 640*620
    float* xp_enc  = e_en_g + 640 * 620;       // 640*4000
    float* xp_dec  = xp_enc + 640 * 4000;      // 640*4000
    float* enc_h   = xp_dec + 640 * 4000;      // 640*1000
    float* dec_h   = enc_h + 640 * 1000;       // 640*1000
    float* c_enc   = dec_h + 640 * 1000;       // 32*1000
    float* c_dec   = c_enc + 32 * 1000;        // 32*1000
    float* Wa      = c_dec + 32 * 1000;        // 640*1000
    float* Ua      = Wa + 640 * 1000;          // 640*1000
    float* scores  = Ua + 640 * 1000;          // 32*20*20
    float* context = scores + Bb * Ss * Tt;    // 640*1000
    float* u       = context + 640 * 1000;     // 640*2000
    float* tmax    = u + 640 * 2000;           // 640*1000
    float* pm      = tmax + 640 * 1000;        // 640*469
    float* ps      = pm + 640 * LTILES;        // 640*469
    float* nll     = ps + 640 * LTILES;        // 640

    // zero the LSTM cell states (c_enc, c_dec contiguous)
    hipMemsetAsync(c_enc, 0, 2 * 32 * 1000 * sizeof(float), stream);

    dim3 blk(256);

    // embedding gathers
    gather_emb<<<dim3((640 * 155 + 255) / 256), blk, 0, stream>>>(
        (const float4*)emb_de, x, Ss, (float4*)e_de_g);
    gather_emb<<<dim3((640 * 155 + 255) / 256), blk, 0, stream>>>(
        (const float4*)emb_en, y, Tt + 1, (float4*)e_en_g);

    // xp = e @ Wih^T + b   [640, 4000], K=620
    gemm64<0><<<dim3(63, 10), blk, 0, stream>>>(e_de_g, enc_Wih, enc_b, xp_enc,
                                                nullptr, nullptr, 640, 4000, 620, 0);
    gemm64<0><<<dim3(63, 10), blk, 0, stream>>>(e_en_g, dec_Wih, dec_b, xp_dec,
                                                nullptr, nullptr, 640, 4000, 620, 0);

    // LSTM recurrences (20 sequential steps each)
    for (int t = 0; t < Tt; ++t)
        lstm_step<<<dim3(4, 16), blk, 0, stream>>>(xp_enc, enc_Whh, c_enc, enc_h, t);
    for (int t = 0; t < Tt; ++t)
        lstm_step<<<dim3(4, 16), blk, 0, stream>>>(xp_dec, dec_Whh, c_dec, dec_h, t);

    // attention projections [640,1000], K=1000
    gemm64<0><<<dim3(16, 10), blk, 0, stream>>>(dec_h, Wa_w, Wa_b, Wa,
                                                nullptr, nullptr, 640, 1000, 1000, 0);
    gemm64<0><<<dim3(16, 10), blk, 0, stream>>>(enc_h, Ua_w, Ua_b, Ua,
                                                nullptr, nullptr, 640, 1000, 1000, 0);

    attn_scores<<<dim3(3200), blk, 0, stream>>>(Ua, Wa, Va_w, Va_b, scores);
    softmax_context<<<dim3(640), blk, 0, stream>>>(scores, enc_h, context);

    // u = dec_h@U^T + U_b + e_en@V^T + V_b + context@C^T + C_b   [640, 2000]
    gemm64<0><<<dim3(32, 10), blk, 0, stream>>>(dec_h, U_w, U_b, u,
                                                nullptr, nullptr, 640, 2000, 1000, 0);
    gemm64<0><<<dim3(32, 10), blk, 0, stream>>>(e_en_g, V_w, V_b, u,
                                                nullptr, nullptr, 640, 2000, 620, 1);
    gemm64<0><<<dim3(32, 10), blk, 0, stream>>>(context, C_w, C_b, u,
                                                nullptr, nullptr, 640, 2000, 1000, 1);

    maxout<<<dim3((640 * 1000 + 255) / 256), blk, 0, stream>>>(u, tmax);

    // logits GEMM fused with per-tile logsumexp stats  [640, 30000], K=1000
    gemm64<1><<<dim3(LTILES, 10), blk, 0, stream>>>(tmax, W_w, W_b, nullptr,
                                                    pm, ps, 640, VEN_, 1000, 0);

    nll_kernel<<<dim3(640), blk, 0, stream>>>(pm, ps, tmax, W_w, W_b, y, nll);
    loss_kernel<<<dim3(1), blk, 0, stream>>>(nll, (float*)d_out);
}

// Round 2
// 2396.318 us; speedup vs baseline: 2.9023x; 2.9023x over previous
//
#include <hip/hip_runtime.h>
#include <math.h>

#define VEN_  30000
#define Dd    620
#define Hh    1000
#define Gg    4000   // 4*H
#define Mm    1000
#define Bb    32
#define Ss    20
#define Tt    20
#define LTILES 469   // ceil(30000/64)

__device__ __forceinline__ float sigf(float x) { return 1.0f / (1.0f + __expf(-x)); }
__device__ __forceinline__ float dot4(float4 a, float4 b) {
    return a.x * b.x + a.y * b.y + a.z * b.z + a.w * b.w;
}

// ---------------- embedding gather (float4, rows of 620 = 155 float4) -------
__global__ void gather_emb(const float4* __restrict__ emb, const int* __restrict__ toks,
                           int tstride, float4* __restrict__ out) {
    int i = blockIdx.x * blockDim.x + threadIdx.x;   // over 640*155
    if (i >= Bb * Tt * 155) return;
    int row = i / 155, d4 = i % 155;
    int b = row / Tt, t = row % Tt;
    int tok = toks[b * tstride + t];
    out[row * 155 + d4] = emb[tok * 155 + d4];
}

// ---------------- generic tiled GEMM: C[M,N] = A[M,K] * B[N,K]^T (+bias) ----
// grid = (rowTiles, colTiles)  -- row-tiles fastest so B-panel sharers are
// co-resident (B streamed once through L2/L3).
// MODE 0: write C (beta ? C += : C =), with per-col bias
// MODE 1: logits stats epilogue: per-(row, 64-col tile) max & sumexp partials
#define FMA16(a, b)                                                                         \
    acc[0][0] += a.x * b.x; acc[0][1] += a.x * b.y; acc[0][2] += a.x * b.z; acc[0][3] += a.x * b.w; \
    acc[1][0] += a.y * b.x; acc[1][1] += a.y * b.y; acc[1][2] += a.y * b.z; acc[1][3] += a.y * b.w; \
    acc[2][0] += a.z * b.x; acc[2][1] += a.z * b.y; acc[2][2] += a.z * b.z; acc[2][3] += a.z * b.w; \
    acc[3][0] += a.w * b.x; acc[3][1] += a.w * b.y; acc[3][2] += a.w * b.z; acc[3][3] += a.w * b.w;

template <int MODE>
__global__ __launch_bounds__(256) void gemm64(
    const float* __restrict__ A, const float* __restrict__ B,
    const float* __restrict__ bias, float* __restrict__ C,
    float* __restrict__ pm, float* __restrict__ ps,
    int M, int N, int K, int beta)
{
    __shared__ float As[32][68];   // [k][m]
    __shared__ float Bs[32][68];   // [k][n]
    const int tid = threadIdx.x;
    const int tn = tid & 15;       // col quad
    const int tm = tid >> 4;       // row quad 0..15
    const int row0 = blockIdx.x * 64, col0 = blockIdx.y * 64;
    // staging map: lane = row within tile, wave = k-chunk of 8.
    // LDS write bank = (const + lane) % 32 -> 2-way aliasing only (free).
    const int lr  = tid & 63;
    const int lc0 = (tid >> 6) * 8;
    float acc[4][4] = {};

    for (int kk = 0; kk < K; kk += 32) {
        {
            int r = row0 + lr;
            bool kfull = (kk + lc0 + 7 < K);
            if (r < M && kfull) {
                float4 v0 = *(const float4*)&A[(size_t)r * K + kk + lc0];
                float4 v1 = *(const float4*)&A[(size_t)r * K + kk + lc0 + 4];
                As[lc0 + 0][lr] = v0.x; As[lc0 + 1][lr] = v0.y; As[lc0 + 2][lr] = v0.z; As[lc0 + 3][lr] = v0.w;
                As[lc0 + 4][lr] = v1.x; As[lc0 + 5][lr] = v1.y; As[lc0 + 6][lr] = v1.z; As[lc0 + 7][lr] = v1.w;
            } else {
                #pragma unroll
                for (int jj = 0; jj < 8; ++jj) {
                    int c = kk + lc0 + jj;
                    As[lc0 + jj][lr] = (r < M && c < K) ? A[(size_t)r * K + c] : 0.f;
                }
            }
            int rb = col0 + lr;
            if (rb < N && kfull) {
                float4 v0 = *(const float4*)&B[(size_t)rb * K + kk + lc0];
                float4 v1 = *(const float4*)&B[(size_t)rb * K + kk + lc0 + 4];
                Bs[lc0 + 0][lr] = v0.x; Bs[lc0 + 1][lr] = v0.y; Bs[lc0 + 2][lr] = v0.z; Bs[lc0 + 3][lr] = v0.w;
                Bs[lc0 + 4][lr] = v1.x; Bs[lc0 + 5][lr] = v1.y; Bs[lc0 + 6][lr] = v1.z; Bs[lc0 + 7][lr] = v1.w;
            } else {
                #pragma unroll
                for (int jj = 0; jj < 8; ++jj) {
                    int c = kk + lc0 + jj;
                    Bs[lc0 + jj][lr] = (rb < N && c < K) ? B[(size_t)rb * K + c] : 0.f;
                }
            }
        }
        __syncthreads();
        #pragma unroll
        for (int k2 = 0; k2 < 32; ++k2) {
            float4 a = *(const float4*)&As[k2][tm * 4];
            float4 b = *(const float4*)&Bs[k2][tn * 4];
            FMA16(a, b)
        }
        __syncthreads();
    }

    if (MODE == 0) {
        #pragma unroll
        for (int i = 0; i < 4; ++i) {
            int r = row0 + tm * 4 + i;
            if (r >= M) continue;
            #pragma unroll
            for (int jj = 0; jj < 4; ++jj) {
                int c = col0 + tn * 4 + jj;
                if (c >= N) continue;
                float v = acc[i][jj] + (bias ? bias[c] : 0.f);
                if (beta) v += C[(size_t)r * N + c];
                C[(size_t)r * N + c] = v;
            }
        }
    } else {
        #pragma unroll
        for (int i = 0; i < 4; ++i) {
            int r = row0 + tm * 4 + i;
            float vals[4];
            float vmax = -1e30f;
            #pragma unroll
            for (int jj = 0; jj < 4; ++jj) {
                int c = col0 + tn * 4 + jj;
                vals[jj] = (c < N) ? (acc[i][jj] + bias[c]) : -1e30f;
                vmax = fmaxf(vmax, vals[jj]);
            }
            #pragma unroll
            for (int off = 8; off; off >>= 1) vmax = fmaxf(vmax, __shfl_xor(vmax, off, 16));
            float se = 0.f;
            #pragma unroll
            for (int jj = 0; jj < 4; ++jj) {
                int c = col0 + tn * 4 + jj;
                if (c < N) se += __expf(vals[jj] - vmax);
            }
            #pragma unroll
            for (int off = 8; off; off >>= 1) se += __shfl_xor(se, off, 16);
            if (tn == 0 && r < M) {
                pm[(size_t)r * LTILES + blockIdx.y] = vmax;
                ps[(size_t)r * LTILES + blockIdx.y] = se;
            }
        }
    }
}

// ---------------- LSTM step v2: 250 blocks, h_prev staged in LDS -----------
// Block covers 4 hidden columns x 4 gates (16 Whh rows) x all 32 batches.
// thread: jj = tid&15 encodes (gate = jj>>2, colo = jj&3); bb = tid>>4;
// computes gates[(bb, bb+16)][gate*1000 + col] via float4 dots.
// Post-loop 2KB LDS exchange fuses the i/f/g/o update (1 launch per step).
__global__ __launch_bounds__(256) void lstm_step2(
    const float* __restrict__ xp,    // [B, T, 4H] (bias folded in)
    const float* __restrict__ Whh,   // [4H, H]
    float* __restrict__ c_buf,       // [B, H]
    float* __restrict__ hs,          // [B, T, H]
    int t)
{
    __shared__ __align__(16) float hsm[32][Hh];   // 125 KB
    __shared__ float gsm[32][16];
    const int tid = threadIdx.x;

    if (t == 0) {
        for (int i = tid; i < 8000; i += 256)
            ((float4*)hsm)[i] = make_float4(0.f, 0.f, 0.f, 0.f);
    } else {
        for (int i = tid; i < 8000; i += 256) {
            int b = i / 250, k4 = i % 250;
            ((float4*)&hsm[b][0])[k4] =
                ((const float4*)&hs[((size_t)b * Tt + (t - 1)) * Hh])[k4];
        }
    }
    __syncthreads();

    const int jj   = tid & 15;
    const int bb   = tid >> 4;          // 0..15
    const int gate = jj >> 2;
    const int colo = jj & 3;
    const int col  = blockIdx.x * 4 + colo;   // 0..999
    const int j    = gate * Hh + col;

    const float4* w4 = (const float4*)(Whh + (size_t)j * Hh);
    const float4* h0 = (const float4*)&hsm[bb][0];
    const float4* h1 = (const float4*)&hsm[bb + 16][0];
    float acc0 = 0.f, acc1 = 0.f;
    #pragma unroll 5
    for (int k4 = 0; k4 < 250; ++k4) {
        float4 w = w4[k4];
        acc0 += dot4(w, h0[k4]);
        acc1 += dot4(w, h1[k4]);
    }
    gsm[bb][jj]      = acc0;
    gsm[bb + 16][jj] = acc1;
    __syncthreads();

    if (jj < 4) {     // 64 threads: (bb, colo=jj) -> batches bb, bb+16
        const int co = jj;
        const int c  = blockIdx.x * 4 + co;
        #pragma unroll
        for (int bsel = 0; bsel < 2; ++bsel) {
            int b = bb + bsel * 16;
            const float* xpr = xp + ((size_t)b * Tt + t) * Gg;
            float vi = gsm[b][co]      + xpr[c];
            float vf = gsm[b][4 + co]  + xpr[Hh + c];
            float vg = gsm[b][8 + co]  + xpr[2 * Hh + c];
            float vo = gsm[b][12 + co] + xpr[3 * Hh + c];
            float c_old = c_buf[(size_t)b * Hh + c];
            float cn = sigf(vf) * c_old + sigf(vi) * tanhf(vg);
            float hn = sigf(vo) * tanhf(cn);
            c_buf[(size_t)b * Hh + c] = cn;
            hs[((size_t)b * Tt + t) * Hh + c] = hn;
        }
    }
}

// ---------------- attention scores: one wave per (b,s,t) --------------------
__global__ __launch_bounds__(256) void attn_scores(
    const float* __restrict__ Ua, const float* __restrict__ Wa,
    const float* __restrict__ Va_w, const float* __restrict__ Va_b,
    float* __restrict__ scores)
{
    int wave = (blockIdx.x * 256 + threadIdx.x) >> 6;
    int lane = threadIdx.x & 63;
    if (wave >= Bb * Ss * Tt) return;
    int b = wave / (Ss * Tt);
    int rem = wave % (Ss * Tt);
    int s = rem / Tt, t = rem % Tt;
    const float* ua = Ua + (size_t)(b * Ss + s) * Hh;
    const float* wa = Wa + (size_t)(b * Tt + t) * Hh;
    float acc = 0.f;
    for (int h = lane; h < Hh; h += 64)
        acc += tanhf(ua[h] + wa[h]) * Va_w[h];
    #pragma unroll
    for (int off = 32; off; off >>= 1) acc += __shfl_xor(acc, off, 64);
    if (lane == 0) scores[(size_t)(b * Ss + s) * Tt + t] = acc + Va_b[0];
}

// ---------------- softmax over s (20) + context --------------------------
__global__ __launch_bounds__(256) void softmax_context(
    const float* __restrict__ scores, const float* __restrict__ enc_h,
    float* __restrict__ context)
{
    __shared__ float w[Ss];
    int b = blockIdx.x / Tt, t = blockIdx.x % Tt;
    if (threadIdx.x == 0) {
        float sc[Ss];
        float mx = -1e30f;
        for (int s = 0; s < Ss; ++s) {
            sc[s] = scores[(size_t)(b * Ss + s) * Tt + t];
            mx = fmaxf(mx, sc[s]);
        }
        float sum = 0.f;
        for (int s = 0; s < Ss; ++s) { float e = __expf(sc[s] - mx); w[s] = e; sum += e; }
        float inv = 1.f / sum;
        for (int s = 0; s < Ss; ++s) w[s] *= inv;
    }
    __syncthreads();
    for (int h = threadIdx.x; h < Hh; h += 256) {
        float acc = 0.f;
        #pragma unroll
        for (int s = 0; s < Ss; ++s)
            acc += w[s] * enc_h[(size_t)(b * Ss + s) * Hh + h];
        context[(size_t)(b * Tt + t) * Hh + h] = acc;
    }
}

// ---------------- maxout over pairs ---------------------------------------
__global__ void maxout(const float* __restrict__ u, float* __restrict__ tmax) {
    int i = blockIdx.x * blockDim.x + threadIdx.x;
    if (i >= Bb * Tt * Mm) return;
    int row = i / Mm, m = i % Mm;
    tmax[i] = fmaxf(u[(size_t)row * 2 * Mm + 2 * m], u[(size_t)row * 2 * Mm + 2 * m + 1]);
}

// ---------------- per-row NLL from logsumexp partials ----------------------
__global__ __launch_bounds__(256) void nll_kernel(
    const float* __restrict__ pm, const float* __restrict__ ps,
    const float* __restrict__ tmax, const float* __restrict__ Ww,
    const float* __restrict__ Wb, const int* __restrict__ y,
    float* __restrict__ nll)
{
    __shared__ float sm[4];
    int row = blockIdx.x;
    int tid = threadIdx.x;
    float mx = -1e30f;
    for (int i = tid; i < LTILES; i += 256) mx = fmaxf(mx, pm[(size_t)row * LTILES + i]);
    #pragma unroll
    for (int off = 32; off; off >>= 1) mx = fmaxf(mx, __shfl_xor(mx, off, 64));
    if ((tid & 63) == 0) sm[tid >> 6] = mx;
    __syncthreads();
    mx = fmaxf(fmaxf(sm[0], sm[1]), fmaxf(sm[2], sm[3]));
    __syncthreads();
    float s = 0.f;
    for (int i = tid; i < LTILES; i += 256)
        s += ps[(size_t)row * LTILES + i] * __expf(pm[(size_t)row * LTILES + i] - mx);
    #pragma unroll
    for (int off = 32; off; off >>= 1) s += __shfl_xor(s, off, 64);
    if ((tid & 63) == 0) sm[tid >> 6] = s;
    __syncthreads();
    s = sm[0] + sm[1] + sm[2] + sm[3];
    __syncthreads();
    int b = row / Tt, t = row % Tt;
    int lab = y[b * (Tt + 1) + t + 1];
    float d = 0.f;
    for (int m = tid; m < Mm; m += 256)
        d += tmax[(size_t)row * Mm + m] * Ww[(size_t)lab * Mm + m];
    #pragma unroll
    for (int off = 32; off; off >>= 1) d += __shfl_xor(d, off, 64);
    if ((tid & 63) == 0) sm[tid >> 6] = d;
    __syncthreads();
    d = sm[0] + sm[1] + sm[2] + sm[3] + Wb[lab];
    if (tid == 0) nll[row] = (mx + logf(s)) - d;
}

// ---------------- final loss: sum(nll)/B -----------------------------------
__global__ void loss_kernel(const float* __restrict__ nll, float* __restrict__ out) {
    __shared__ float sm[4];
    float s = 0.f;
    for (int i = threadIdx.x; i < Bb * Tt; i += 256) s += nll[i];
    #pragma unroll
    for (int off = 32; off; off >>= 1) s += __shfl_xor(s, off, 64);
    if ((threadIdx.x & 63) == 0) sm[threadIdx.x >> 6] = s;
    __syncthreads();
    if (threadIdx.x == 0) out[0] = (sm[0] + sm[1] + sm[2] + sm[3]) / (float)Bb;
}

extern "C" void kernel_launch(void* const* d_in, const int* in_sizes, int n_in,
                              void* d_out, int out_size, void* d_ws, size_t ws_size,
                              hipStream_t stream)
{
    const int* x = (const int*)d_in[0];
    const int* y = (const int*)d_in[1];
    const float* emb_de  = (const float*)d_in[2];
    const float* emb_en  = (const float*)d_in[3];
    const float* enc_Wih = (const float*)d_in[4];
    const float* enc_Whh = (const float*)d_in[5];
    const float* enc_b   = (const float*)d_in[6];
    const float* dec_Wih = (const float*)d_in[7];
    const float* dec_Whh = (const float*)d_in[8];
    const float* dec_b   = (const float*)d_in[9];
    const float* Wa_w = (const float*)d_in[10];
    const float* Wa_b = (const float*)d_in[11];
    const float* Ua_w = (const float*)d_in[12];
    const float* Ua_b = (const float*)d_in[13];
    const float* Va_w = (const float*)d_in[14];
    const float* Va_b = (const float*)d_in[15];
    const float* U_w  = (const float*)d_in[16];
    const float* U_b  = (const float*)d_in[17];
    const float* V_w  = (const float*)d_in[18];
    const float* V_b  = (const float*)d_in[19];
    const float* C_w  = (const float*)d_in[20];
    const float* C_b  = (const float*)d_in[21];
    const float* W_w  = (const float*)d_in[22];
    const float* W_b  = (const float*)d_in[23];

    float* ws = (float*)d_ws;
    float* e_de_g  = ws;                       // 640*620
    float* e_en_g  = e_de_g + 640 * 620;       // 640*620
    float* xp_enc  = e_en_g + 640 * 620;       // 640*4000
    float* xp_dec  = xp_enc + 640 * 4000;      // 640*4000
    float* enc_h   = xp_dec + 640 * 4000;      // 640*1000
    float* dec_h   = enc_h + 640 * 1000;       // 640*1000
    float* c_enc   = dec_h + 640 * 1000;       // 32*1000
    float* c_dec   = c_enc + 32 * 1000;        // 32*1000
    float* Wa      = c_dec + 32 * 1000;        // 640*1000
    float* Ua      = Wa + 640 * 1000;          // 640*1000
    float* scores  = Ua + 640 * 1000;          // 32*20*20
    float* context = scores + Bb * Ss * Tt;    // 640*1000
    float* u       = context + 640 * 1000;     // 640*2000
    float* tmax    = u + 640 * 2000;           // 640*1000
    float* pm      = tmax + 640 * 1000;        // 640*469
    float* ps      = pm + 640 * LTILES;        // 640*469
    float* nll     = ps + 640 * LTILES;        // 640

    hipMemsetAsync(c_enc, 0, 2 * 32 * 1000 * sizeof(float), stream);

    dim3 blk(256);

    gather_emb<<<dim3((640 * 155 + 255) / 256), blk, 0, stream>>>(
        (const float4*)emb_de, x, Ss, (float4*)e_de_g);
    gather_emb<<<dim3((640 * 155 + 255) / 256), blk, 0, stream>>>(
        (const float4*)emb_en, y, Tt + 1, (float4*)e_en_g);

    // xp = e @ Wih^T + b   [640, 4000], K=620   (grid = rowTiles, colTiles)
    gemm64<0><<<dim3(10, 63), blk, 0, stream>>>(e_de_g, enc_Wih, enc_b, xp_enc,
                                                nullptr, nullptr, 640, 4000, 620, 0);
    gemm64<0><<<dim3(10, 63), blk, 0, stream>>>(e_en_g, dec_Wih, dec_b, xp_dec,
                                                nullptr, nullptr, 640, 4000, 620, 0);

    for (int t = 0; t < Tt; ++t)
        lstm_step2<<<dim3(250), blk, 0, stream>>>(xp_enc, enc_Whh, c_enc, enc_h, t);
    for (int t = 0; t < Tt; ++t)
        lstm_step2<<<dim3(250), blk, 0, stream>>>(xp_dec, dec_Whh, c_dec, dec_h, t);

    gemm64<0><<<dim3(10, 16), blk, 0, stream>>>(dec_h, Wa_w, Wa_b, Wa,
                                                nullptr, nullptr, 640, 1000, 1000, 0);
    gemm64<0><<<dim3(10, 16), blk, 0, stream>>>(enc_h, Ua_w, Ua_b, Ua,
                                                nullptr, nullptr, 640, 1000, 1000, 0);

    attn_scores<<<dim3(3200), blk, 0, stream>>>(Ua, Wa, Va_w, Va_b, scores);
    softmax_context<<<dim3(640), blk, 0, stream>>>(scores, enc_h, context);

    gemm64<0><<<dim3(10, 32), blk, 0, stream>>>(dec_h, U_w, U_b, u,
                                                nullptr, nullptr, 640, 2000, 1000, 0);
    gemm64<0><<<dim3(10, 32), blk, 0, stream>>>(e_en_g, V_w, V_b, u,
                                                nullptr, nullptr, 640, 2000, 620, 1);
    gemm64<0><<<dim3(10, 32), blk, 0, stream>>>(context, C_w, C_b, u,
                                                nullptr, nullptr, 640, 2000, 1000, 1);

    maxout<<<dim3((640 * 1000 + 255) / 256), blk, 0, stream>>>(u, tmax);

    gemm64<1><<<dim3(10, LTILES), blk, 0, stream>>>(tmax, W_w, W_b, nullptr,
                                                    pm, ps, 640, VEN_, 1000, 0);

    nll_kernel<<<dim3(640), blk, 0, stream>>>(pm, ps, tmax, W_w, W_b, y, nll);
    loss_kernel<<<dim3(1), blk, 0, stream>>>(nll, (float*)d_out);
}

// Round 3
// 1186.537 us; speedup vs baseline: 5.8615x; 2.0196x over previous
//
#include <hip/hip_runtime.h>
#include <math.h>

#define VEN_  30000
#define Dd    620
#define Hh    1000
#define Gg    4000   // 4*H
#define Mm    1000
#define Bb    32
#define Ss    20
#define Tt    20
#define NST   470    // 2 * ceil(30000/128) stat slots per row

typedef __attribute__((ext_vector_type(8))) short short8b;  // 8 bf16
typedef __attribute__((ext_vector_type(4))) float f32x4;

__device__ __forceinline__ float sigf(float x) { return 1.0f / (1.0f + __expf(-x)); }
__device__ __forceinline__ ushort f2bf(float f) {            // RNE fp32->bf16
    unsigned u = __float_as_uint(f);
    u = (u + 0x7fffu + ((u >> 16) & 1u)) >> 16;
    return (ushort)u;
}
__device__ __forceinline__ float bf2f(ushort u) { return __uint_as_float(((unsigned)u) << 16); }

// ---------------- embedding gather -> bf16, K-padded ------------------------
__global__ void gather_emb_bf16(const float* __restrict__ emb, const int* __restrict__ toks,
                                int tstride, ushort* __restrict__ out, int ostride) {
    int idx = blockIdx.x * 256 + threadIdx.x;   // 640 * 80 chunks of 8
    if (idx >= Bb * Tt * 80) return;
    int row = idx / 80, c8 = (idx % 80) * 8;
    int b = row / Tt, t = row % Tt;
    int tok = toks[b * tstride + t];
    const float* src = emb + (size_t)tok * Dd + c8;
    ushort v[8];
    #pragma unroll
    for (int j = 0; j < 8; ++j) v[j] = (c8 + j < Dd) ? f2bf(src[j]) : (ushort)0;
    *(short8b*)&out[(size_t)row * ostride + c8] = *(short8b*)v;
}

// ---------------- fp32 -> bf16 convert with K padding (for Whh) ------------
__global__ void convert_pad_bf16(const float* __restrict__ in, ushort* __restrict__ out,
                                 int R, int K, int Kp) {
    int idx = blockIdx.x * 256 + threadIdx.x;
    int kp8 = Kp >> 3;
    if (idx >= R * kp8) return;
    int r = idx / kp8, c8 = (idx % kp8) * 8;
    const float* src = in + (size_t)r * K + c8;
    ushort v[8];
    #pragma unroll
    for (int j = 0; j < 8; ++j) v[j] = (c8 + j < K) ? f2bf(src[j]) : (ushort)0;
    *(short8b*)&out[(size_t)r * Kp + c8] = *(short8b*)v;
}

// ---------------- MFMA GEMM: C[M,N] = A_bf16[M,Kp] * B_fp32[N,Ktrue]^T -----
// 128x128 tile, 4 waves (2x2), 4x4 fragments of 16x16x32 each.
// B converted fp32->bf16 during LDS staging. Grid: XCD-swizzled linear ids,
// blocks = 8*MT*ceil(NT/8); same-col-panel row-tiles land on one XCD.
// MODE 0: C = acc + bias (+C if beta). MODE 1: logsumexp partials pm/ps.
template <int MODE>
__global__ __launch_bounds__(256) void gemm_bf16(
    const ushort* __restrict__ A, int lda,
    const float* __restrict__ B, int ldb,          // ldb = Ktrue
    const float* __restrict__ bias,
    float* __restrict__ C, int ldc, int beta,
    float* __restrict__ pm, float* __restrict__ ps,
    int M, int N, int Kp, int Ktrue, int MT, int NT)
{
    int id = blockIdx.x;
    int x = id & 7, q = id >> 3;
    int pi = q / MT, r = q % MT;
    int p = pi * 8 + x;
    if (p >= NT) return;
    const int row0 = r * 128, col0 = p * 128;

    __shared__ ushort As[128][32];
    __shared__ ushort Bs[128][32];
    const int tid = threadIdx.x;
    const int w = tid >> 6;
    const int l = tid & 63;
    const int wm = w >> 1, wn = w & 1;
    const int lhi = l >> 4, llo = l & 15;

    f32x4 acc[4][4] = {};

    for (int kk = 0; kk < Kp; kk += 32) {
        #pragma unroll
        for (int it = 0; it < 2; ++it) {
            int idx = tid + it * 256;            // 0..511
            int rr = idx >> 2, cq = (idx & 3) * 8;
            // A: already bf16, padded to Kp
            {
                int ra = row0 + rr; if (ra > M - 1) ra = M - 1;
                const ushort* ga = A + (size_t)ra * lda + kk + cq;
                *(short8b*)&As[rr][cq] = *(const short8b*)ga;
            }
            // B: fp32 -> bf16 on the fly, zero beyond Ktrue
            {
                int rb = col0 + rr; if (rb > N - 1) rb = N - 1;
                const float* gb = B + (size_t)rb * ldb + kk + cq;
                ushort tmp[8];
                if (kk + cq + 7 < Ktrue) {
                    float4 v0 = *(const float4*)gb;
                    float4 v1 = *(const float4*)(gb + 4);
                    tmp[0] = f2bf(v0.x); tmp[1] = f2bf(v0.y); tmp[2] = f2bf(v0.z); tmp[3] = f2bf(v0.w);
                    tmp[4] = f2bf(v1.x); tmp[5] = f2bf(v1.y); tmp[6] = f2bf(v1.z); tmp[7] = f2bf(v1.w);
                } else {
                    #pragma unroll
                    for (int j = 0; j < 8; ++j) {
                        int c = kk + cq + j;
                        tmp[j] = (c < Ktrue) ? f2bf(gb[j]) : (ushort)0;
                    }
                }
                *(short8b*)&Bs[rr][cq] = *(short8b*)tmp;
            }
        }
        __syncthreads();
        short8b af[4], bg[4];
        #pragma unroll
        for (int i = 0; i < 4; ++i) {
            af[i] = *(short8b*)&As[wm * 64 + i * 16 + llo][lhi * 8];
            bg[i] = *(short8b*)&Bs[wn * 64 + i * 16 + llo][lhi * 8];
        }
        #pragma unroll
        for (int i = 0; i < 4; ++i)
            #pragma unroll
            for (int j = 0; j < 4; ++j)
                acc[i][j] = __builtin_amdgcn_mfma_f32_16x16x32_bf16(af[i], bg[j], acc[i][j], 0, 0, 0);
        __syncthreads();
    }

    if (MODE == 0) {
        #pragma unroll
        for (int i = 0; i < 4; ++i) {
            #pragma unroll
            for (int reg = 0; reg < 4; ++reg) {
                int row = row0 + wm * 64 + i * 16 + lhi * 4 + reg;
                if (row >= M) continue;
                #pragma unroll
                for (int j = 0; j < 4; ++j) {
                    int col = col0 + wn * 64 + j * 16 + llo;
                    if (col < N) {
                        float v = acc[i][j][reg] + (bias ? bias[col] : 0.f);
                        if (beta) v += C[(size_t)row * ldc + col];
                        C[(size_t)row * ldc + col] = v;
                    }
                }
            }
        }
    } else {
        #pragma unroll
        for (int i = 0; i < 4; ++i) {
            #pragma unroll
            for (int reg = 0; reg < 4; ++reg) {
                int row = row0 + wm * 64 + i * 16 + lhi * 4 + reg;
                float vals[4], vmax = -1e30f;
                #pragma unroll
                for (int j = 0; j < 4; ++j) {
                    int col = col0 + wn * 64 + j * 16 + llo;
                    vals[j] = (col < N) ? (acc[i][j][reg] + bias[col]) : -1e30f;
                    vmax = fmaxf(vmax, vals[j]);
                }
                #pragma unroll
                for (int off = 8; off; off >>= 1) vmax = fmaxf(vmax, __shfl_xor(vmax, off, 16));
                float se = 0.f;
                #pragma unroll
                for (int j = 0; j < 4; ++j) {
                    int col = col0 + wn * 64 + j * 16 + llo;
                    if (col < N) se += __expf(vals[j] - vmax);
                }
                #pragma unroll
                for (int off = 8; off; off >>= 1) se += __shfl_xor(se, off, 16);
                if (llo == 0 && row < M) {
                    pm[(size_t)row * NST + p * 2 + wn] = vmax;
                    ps[(size_t)row * NST + p * 2 + wn] = se;
                }
            }
        }
    }
}

// ---------------- LSTM step via MFMA ----------------------------------------
// 63 blocks x 16 hidden cols; wave g computes gate g for 16 cols x 32 batches.
// G = h_prev(bf16) @ Whh_b^T  via 16x16x32 MFMA, depth-4 pipelined global loads.
// Fused i/f/g/o update through an 8KB LDS exchange. h written as bf16 (padded).
__global__ __launch_bounds__(256) void lstm_mfma(
    const float* __restrict__ xp,      // [B*T, 4000] fp32, row = b*Tt+t
    const ushort* __restrict__ Whh_b,  // [4000][1024] bf16, padded
    float* __restrict__ c_buf,         // [32][1000] fp32
    ushort* __restrict__ hs_b,         // rows b*Tt+t, stride hstride, 1024 cols used
    int hstride, int t)
{
    __shared__ float gsm[4][32][16];
    const int tid = threadIdx.x;
    const int g = tid >> 6, l = tid & 63;
    const int lhi = l >> 4, llo = l & 15;
    const int j0 = blockIdx.x * 16;
    const int j = j0 + llo;
    const int jc = (j < Hh) ? j : (Hh - 1);

    f32x4 acc0 = {0.f, 0.f, 0.f, 0.f};
    f32x4 acc1 = {0.f, 0.f, 0.f, 0.f};

    if (t > 0) {
        const ushort* wp  = Whh_b + (size_t)(g * Hh + jc) * 1024 + lhi * 8;
        const ushort* h0p = hs_b + ((size_t)llo * Tt + (t - 1)) * hstride + lhi * 8;
        const ushort* h1p = hs_b + ((size_t)(16 + llo) * Tt + (t - 1)) * hstride + lhi * 8;
        short8b wreg[4], a0r[4], a1r[4];
        #pragma unroll
        for (int pp = 0; pp < 4; ++pp) {
            wreg[pp] = *(const short8b*)(wp  + pp * 32);
            a0r[pp]  = *(const short8b*)(h0p + pp * 32);
            a1r[pp]  = *(const short8b*)(h1p + pp * 32);
        }
        #pragma unroll 4
        for (int kk = 0; kk < 32; ++kk) {
            short8b wc = wreg[kk & 3], a0 = a0r[kk & 3], a1 = a1r[kk & 3];
            if (kk + 4 < 32) {
                wreg[kk & 3] = *(const short8b*)(wp  + (kk + 4) * 32);
                a0r[kk & 3]  = *(const short8b*)(h0p + (kk + 4) * 32);
                a1r[kk & 3]  = *(const short8b*)(h1p + (kk + 4) * 32);
            }
            acc0 = __builtin_amdgcn_mfma_f32_16x16x32_bf16(a0, wc, acc0, 0, 0, 0);
            acc1 = __builtin_amdgcn_mfma_f32_16x16x32_bf16(a1, wc, acc1, 0, 0, 0);
        }
    }
    #pragma unroll
    for (int reg = 0; reg < 4; ++reg) {
        gsm[g][lhi * 4 + reg][llo]      = acc0[reg];
        gsm[g][16 + lhi * 4 + reg][llo] = acc1[reg];
    }
    __syncthreads();
    #pragma unroll
    for (int kI = 0; kI < 2; ++kI) {
        int idx = tid + kI * 256;
        int b = idx >> 4, jj = idx & 15;
        int jw = j0 + jj;
        if (jw < Hh) {
            const float* xpr = xp + ((size_t)b * Tt + t) * Gg;
            float vi = gsm[0][b][jj] + xpr[jw];
            float vf = gsm[1][b][jj] + xpr[Hh + jw];
            float vg = gsm[2][b][jj] + xpr[2 * Hh + jw];
            float vo = gsm[3][b][jj] + xpr[3 * Hh + jw];
            float co = c_buf[(size_t)b * Hh + jw];
            float cn = sigf(vf) * co + sigf(vi) * tanhf(vg);
            float hn = sigf(vo) * tanhf(cn);
            c_buf[(size_t)b * Hh + jw] = cn;
            hs_b[((size_t)b * Tt + t) * hstride + jw] = f2bf(hn);
        }
    }
}

// ---------------- attention scores: one wave per (b,s,t) --------------------
__global__ __launch_bounds__(256) void attn_scores(
    const float* __restrict__ Ua, const float* __restrict__ Wa,
    const float* __restrict__ Va_w, const float* __restrict__ Va_b,
    float* __restrict__ scores)
{
    int wave = (blockIdx.x * 256 + threadIdx.x) >> 6;
    int lane = threadIdx.x & 63;
    if (wave >= Bb * Ss * Tt) return;
    int b = wave / (Ss * Tt);
    int rem = wave % (Ss * Tt);
    int s = rem / Tt, t = rem % Tt;
    const float* ua = Ua + (size_t)(b * Ss + s) * Hh;
    const float* wa = Wa + (size_t)(b * Tt + t) * Hh;
    float acc = 0.f;
    for (int h = lane; h < Hh; h += 64)
        acc += tanhf(ua[h] + wa[h]) * Va_w[h];
    #pragma unroll
    for (int off = 32; off; off >>= 1) acc += __shfl_xor(acc, off, 64);
    if (lane == 0) scores[(size_t)(b * Ss + s) * Tt + t] = acc + Va_b[0];
}

// ---------------- softmax over s + context (bf16 in, bf16 out into A_cat) --
__global__ __launch_bounds__(256) void softmax_context(
    const float* __restrict__ scores, const ushort* __restrict__ enc_hb,
    ushort* __restrict__ ctx_out /* A_cat + 1664 */, int ostride)
{
    __shared__ float w[Ss];
    int b = blockIdx.x / Tt, t = blockIdx.x % Tt;
    if (threadIdx.x == 0) {
        float sc[Ss];
        float mx = -1e30f;
        for (int s = 0; s < Ss; ++s) {
            sc[s] = scores[(size_t)(b * Ss + s) * Tt + t];
            mx = fmaxf(mx, sc[s]);
        }
        float sum = 0.f;
        for (int s = 0; s < Ss; ++s) { float e = __expf(sc[s] - mx); w[s] = e; sum += e; }
        float inv = 1.f / sum;
        for (int s = 0; s < Ss; ++s) w[s] *= inv;
    }
    __syncthreads();
    for (int h = threadIdx.x; h < Hh; h += 256) {
        float acc = 0.f;
        #pragma unroll
        for (int s = 0; s < Ss; ++s)
            acc += w[s] * bf2f(enc_hb[((size_t)b * Ss + s) * 1024 + h]);
        ctx_out[(size_t)(b * Tt + t) * ostride + h] = f2bf(acc);
    }
}

// ---------------- maxout: u[640][2000] -> tmax fp32 [640][1000] + bf16 pad --
__global__ void maxout(const float* __restrict__ u, float* __restrict__ tmax,
                       ushort* __restrict__ tmax_b) {
    int i = blockIdx.x * blockDim.x + threadIdx.x;   // over 640*1024
    if (i >= Bb * Tt * 1024) return;
    int row = i >> 10, m = i & 1023;
    ushort tb = 0;
    if (m < Mm) {
        float v = fmaxf(u[(size_t)row * 2 * Mm + 2 * m], u[(size_t)row * 2 * Mm + 2 * m + 1]);
        tmax[(size_t)row * Mm + m] = v;
        tb = f2bf(v);
    }
    tmax_b[(size_t)row * 1024 + m] = tb;
}

// ---------------- per-row NLL from logsumexp partials ----------------------
__global__ __launch_bounds__(256) void nll_kernel(
    const float* __restrict__ pm, const float* __restrict__ ps,
    const float* __restrict__ tmax, const float* __restrict__ Ww,
    const float* __restrict__ Wb, const int* __restrict__ y,
    float* __restrict__ nll)
{
    __shared__ float sm[4];
    int row = blockIdx.x;
    int tid = threadIdx.x;
    float mx = -1e30f;
    for (int i = tid; i < NST; i += 256) mx = fmaxf(mx, pm[(size_t)row * NST + i]);
    #pragma unroll
    for (int off = 32; off; off >>= 1) mx = fmaxf(mx, __shfl_xor(mx, off, 64));
    if ((tid & 63) == 0) sm[tid >> 6] = mx;
    __syncthreads();
    mx = fmaxf(fmaxf(sm[0], sm[1]), fmaxf(sm[2], sm[3]));
    __syncthreads();
    float s = 0.f;
    for (int i = tid; i < NST; i += 256)
        s += ps[(size_t)row * NST + i] * __expf(pm[(size_t)row * NST + i] - mx);
    #pragma unroll
    for (int off = 32; off; off >>= 1) s += __shfl_xor(s, off, 64);
    if ((tid & 63) == 0) sm[tid >> 6] = s;
    __syncthreads();
    s = sm[0] + sm[1] + sm[2] + sm[3];
    __syncthreads();
    int b = row / Tt, t = row % Tt;
    int lab = y[b * (Tt + 1) + t + 1];
    float d = 0.f;
    for (int m = tid; m < Mm; m += 256)
        d += tmax[(size_t)row * Mm + m] * Ww[(size_t)lab * Mm + m];
    #pragma unroll
    for (int off = 32; off; off >>= 1) d += __shfl_xor(d, off, 64);
    if ((tid & 63) == 0) sm[tid >> 6] = d;
    __syncthreads();
    d = sm[0] + sm[1] + sm[2] + sm[3] + Wb[lab];
    if (tid == 0) nll[row] = (mx + logf(s)) - d;
}

__global__ void loss_kernel(const float* __restrict__ nll, float* __restrict__ out) {
    __shared__ float sm[4];
    float s = 0.f;
    for (int i = threadIdx.x; i < Bb * Tt; i += 256) s += nll[i];
    #pragma unroll
    for (int off = 32; off; off >>= 1) s += __shfl_xor(s, off, 64);
    if ((threadIdx.x & 63) == 0) sm[threadIdx.x >> 6] = s;
    __syncthreads();
    if (threadIdx.x == 0) out[0] = (sm[0] + sm[1] + sm[2] + sm[3]) / (float)Bb;
}

static inline int gemm_blocks(int MT, int NT) { return 8 * MT * ((NT + 7) / 8); }

extern "C" void kernel_launch(void* const* d_in, const int* in_sizes, int n_in,
                              void* d_out, int out_size, void* d_ws, size_t ws_size,
                              hipStream_t stream)
{
    const int* x = (const int*)d_in[0];
    const int* y = (const int*)d_in[1];
    const float* emb_de  = (const float*)d_in[2];
    const float* emb_en  = (const float*)d_in[3];
    const float* enc_Wih = (const float*)d_in[4];
    const float* enc_Whh = (const float*)d_in[5];
    const float* enc_b   = (const float*)d_in[6];
    const float* dec_Wih = (const float*)d_in[7];
    const float* dec_Whh = (const float*)d_in[8];
    const float* dec_b   = (const float*)d_in[9];
    const float* Wa_w = (const float*)d_in[10];
    const float* Wa_b = (const float*)d_in[11];
    const float* Ua_w = (const float*)d_in[12];
    const float* Ua_b = (const float*)d_in[13];
    const float* Va_w = (const float*)d_in[14];
    const float* Va_b = (const float*)d_in[15];
    const float* U_w  = (const float*)d_in[16];
    const float* U_b  = (const float*)d_in[17];
    const float* V_w  = (const float*)d_in[18];
    const float* V_b  = (const float*)d_in[19];
    const float* C_w  = (const float*)d_in[20];
    const float* C_b  = (const float*)d_in[21];
    const float* W_w  = (const float*)d_in[22];
    const float* W_b  = (const float*)d_in[23];

    char* base = (char*)d_ws;
    size_t off = 0;
    auto alloc = [&](size_t bytes) { char* p = base + off; off += (bytes + 255) & ~(size_t)255; return p; };

    float*  xp_enc   = (float*)alloc(640ull * 4000 * 4);   // also reused: u, tmax
    float*  xp_dec   = (float*)alloc(640ull * 4000 * 4);   // also reused: tmax_b
    float*  Wa       = (float*)alloc(640ull * 1000 * 4);
    float*  Ua       = (float*)alloc(640ull * 1000 * 4);
    float*  scores   = (float*)alloc((size_t)Bb * Ss * Tt * 4);
    float*  pm       = (float*)alloc(640ull * NST * 4);
    float*  ps       = (float*)alloc(640ull * NST * 4);
    float*  nll      = (float*)alloc(640ull * 4);
    float*  c_enc    = (float*)alloc(32ull * 1000 * 4);
    float*  c_dec    = (float*)alloc(32ull * 1000 * 4);
    ushort* e_de_b   = (ushort*)alloc(640ull * 640 * 2);
    ushort* A_cat    = (ushort*)alloc(640ull * 2688 * 2);  // [dec_h 1024 | e_en 640 | ctx 1024]
    ushort* hs_enc_b = (ushort*)alloc(640ull * 1024 * 2);
    ushort* whh_enc_b= (ushort*)alloc(4000ull * 1024 * 2);
    ushort* whh_dec_b= (ushort*)alloc(4000ull * 1024 * 2);

    // aliases (lifetimes disjoint): u & tmax overlay xp_enc; tmax_b overlays xp_dec
    float*  u      = xp_enc;                               // 640*2000 f32
    float*  tmax   = xp_enc + 640ull * 2000;               // 640*1000 f32
    ushort* tmax_b = (ushort*)xp_dec;                      // 640*1024 bf16

    dim3 blk(256);

    hipMemsetAsync(c_enc, 0, 2ull * 32 * 1000 * 4, stream);          // c_enc + c_dec contiguous
    hipMemsetAsync(hs_enc_b, 0, 640ull * 1024 * 2, stream);
    hipMemsetAsync(A_cat, 0, 640ull * 2688 * 2, stream);

    // Whh -> bf16 (padded K 1000->1024)
    convert_pad_bf16<<<dim3(2000), blk, 0, stream>>>(enc_Whh, whh_enc_b, 4000, 1000, 1024);
    convert_pad_bf16<<<dim3(2000), blk, 0, stream>>>(dec_Whh, whh_dec_b, 4000, 1000, 1024);

    // embeddings -> bf16 (e_en goes straight into A_cat cols 1024..1663)
    gather_emb_bf16<<<dim3(200), blk, 0, stream>>>(emb_de, x, Ss, e_de_b, 640);
    gather_emb_bf16<<<dim3(200), blk, 0, stream>>>(emb_en, y, Tt + 1, A_cat + 1024, 2688);

    // xp = e @ Wih^T + b   [640,4000] fp32
    gemm_bf16<0><<<dim3(gemm_blocks(5, 32)), blk, 0, stream>>>(
        e_de_b, 640, enc_Wih, 620, enc_b, xp_enc, 4000, 0,
        nullptr, nullptr, 640, 4000, 640, 620, 5, 32);
    gemm_bf16<0><<<dim3(gemm_blocks(5, 32)), blk, 0, stream>>>(
        A_cat + 1024, 2688, dec_Wih, 620, dec_b, xp_dec, 4000, 0,
        nullptr, nullptr, 640, 4000, 640, 620, 5, 32);

    // LSTM recurrences: enc h -> hs_enc_b, dec h -> A_cat cols 0..1023
    for (int t = 0; t < Tt; ++t)
        lstm_mfma<<<dim3(63), blk, 0, stream>>>(xp_enc, whh_enc_b, c_enc, hs_enc_b, 1024, t);
    for (int t = 0; t < Tt; ++t)
        lstm_mfma<<<dim3(63), blk, 0, stream>>>(xp_dec, whh_dec_b, c_dec, A_cat, 2688, t);

    // attention projections (fp32 out)
    gemm_bf16<0><<<dim3(gemm_blocks(5, 8)), blk, 0, stream>>>(
        A_cat, 2688, Wa_w, 1000, Wa_b, Wa, 1000, 0,
        nullptr, nullptr, 640, 1000, 1024, 1000, 5, 8);
    gemm_bf16<0><<<dim3(gemm_blocks(5, 8)), blk, 0, stream>>>(
        hs_enc_b, 1024, Ua_w, 1000, Ua_b, Ua, 1000, 0,
        nullptr, nullptr, 640, 1000, 1024, 1000, 5, 8);

    attn_scores<<<dim3(3200), blk, 0, stream>>>(Ua, Wa, Va_w, Va_b, scores);
    softmax_context<<<dim3(640), blk, 0, stream>>>(scores, hs_enc_b, A_cat + 1664, 2688);

    // u = dec_h@U^T + e_en@V^T + ctx@C^T + biases   [640,2000] fp32
    gemm_bf16<0><<<dim3(gemm_blocks(5, 16)), blk, 0, stream>>>(
        A_cat, 2688, U_w, 1000, U_b, u, 2000, 0,
        nullptr, nullptr, 640, 2000, 1024, 1000, 5, 16);
    gemm_bf16<0><<<dim3(gemm_blocks(5, 16)), blk, 0, stream>>>(
        A_cat + 1024, 2688, V_w, 620, V_b, u, 2000, 1,
        nullptr, nullptr, 640, 2000, 640, 620, 5, 16);
    gemm_bf16<0><<<dim3(gemm_blocks(5, 16)), blk, 0, stream>>>(
        A_cat + 1664, 2688, C_w, 1000, C_b, u, 2000, 1,
        nullptr, nullptr, 640, 2000, 1024, 1000, 5, 16);

    maxout<<<dim3((640 * 1024 + 255) / 256), blk, 0, stream>>>(u, tmax, tmax_b);

    // logits GEMM + fused logsumexp partials
    gemm_bf16<1><<<dim3(gemm_blocks(5, 235)), blk, 0, stream>>>(
        tmax_b, 1024, W_w, 1000, W_b, nullptr, 0, 0,
        pm, ps, 640, VEN_, 1024, 1000, 5, 235);

    nll_kernel<<<dim3(640), blk, 0, stream>>>(pm, ps, tmax, W_w, W_b, y, nll);
    loss_kernel<<<dim3(1), blk, 0, stream>>>(nll, (float*)d_out);
}

// Round 4
// 699.731 us; speedup vs baseline: 9.9393x; 1.6957x over previous
//
#include <hip/hip_runtime.h>
#include <math.h>

#define VEN_  30000
#define Dd    620
#define Hh    1000
#define Gg    4000   // 4*H
#define Mm    1000
#define Bb    32
#define Ss    20
#define Tt    20
#define NST   470    // 2 * ceil(30000/128) stat slots per row

typedef __attribute__((ext_vector_type(8))) short short8b;  // 8 bf16
typedef __attribute__((ext_vector_type(4))) float f32x4;

typedef __attribute__((address_space(1))) void GASV;
typedef __attribute__((address_space(3))) void LASV;
#define GLOAD_LDS16(g, l) \
    __builtin_amdgcn_global_load_lds((GASV*)(const void*)(g), (LASV*)(void*)(l), 16, 0, 0)

__device__ __forceinline__ float sigf(float x) { return 1.0f / (1.0f + __expf(-x)); }
__device__ __forceinline__ ushort f2bf(float f) {            // RNE fp32->bf16
    unsigned u = __float_as_uint(f);
    u = (u + 0x7fffu + ((u >> 16) & 1u)) >> 16;
    return (ushort)u;
}
__device__ __forceinline__ float bf2f(ushort u) { return __uint_as_float(((unsigned)u) << 16); }

// ---------------- fp32 -> bf16 convert, K-padded, arbitrary out stride ------
__global__ void conv_bf16(const float* __restrict__ in, int K,
                          ushort* __restrict__ out, int ostride, int Kp, int total) {
    int idx = blockIdx.x * 256 + threadIdx.x;
    if (idx >= total) return;                 // total = R * Kp/8
    int kp8 = Kp >> 3;
    int rr = idx / kp8, c8 = (idx % kp8) * 8;
    const float* src = in + (size_t)rr * K + c8;
    ushort v[8];
    #pragma unroll
    for (int j = 0; j < 8; ++j) v[j] = (c8 + j < K) ? f2bf(src[j]) : (ushort)0;
    *(short8b*)&out[(size_t)rr * ostride + c8] = *(short8b*)v;
}

__global__ void add3(const float* __restrict__ a, const float* __restrict__ b,
                     const float* __restrict__ c, float* __restrict__ o, int n) {
    int i = blockIdx.x * 256 + threadIdx.x;
    if (i < n) o[i] = a[i] + b[i] + c[i];
}

// ---------------- embedding gather -> bf16, K-padded ------------------------
__global__ void gather_emb_bf16(const float* __restrict__ emb, const int* __restrict__ toks,
                                int tstride, ushort* __restrict__ out, int ostride) {
    int idx = blockIdx.x * 256 + threadIdx.x;   // 640 * 80 chunks of 8
    if (idx >= Bb * Tt * 80) return;
    int row = idx / 80, c8 = (idx % 80) * 8;
    int b = row / Tt, t = row % Tt;
    int tok = toks[b * tstride + t];
    const float* src = emb + (size_t)tok * Dd + c8;
    ushort v[8];
    #pragma unroll
    for (int j = 0; j < 8; ++j) v[j] = (c8 + j < Dd) ? f2bf(src[j]) : (ushort)0;
    *(short8b*)&out[(size_t)row * ostride + c8] = *(short8b*)v;
}

// ---------------- MFMA GEMM (m97 structure): C[M,N] = A[M,Kp] * B[N,Kp]^T ---
// Both operands bf16, K-padded to 64. 128x128 tile, 4 waves, BK=64,
// global_load_lds 16B direct staging with XOR slot swizzle (slot = c ^ (row&7))
// applied on the pre-swizzled GLOBAL source + swizzled ds_read (rule #21).
// Grid: 1D, bijective XCD swizzle (m204), col-panel-major for B-panel reuse.
// MODE 0: C = acc + bias. MODE 1: per-(row, 64-col) logsumexp partials.
template <int MODE>
__global__ __launch_bounds__(256) void gemm_nt(
    const ushort* __restrict__ A, int lda,
    const ushort* __restrict__ B, int ldb,
    const float* __restrict__ bias,
    float* __restrict__ C, int ldc,
    float* __restrict__ pm, float* __restrict__ ps,
    int M, int N, int Kp, int MT)
{
    __shared__ __align__(16) ushort As[128 * 64];
    __shared__ __align__(16) ushort Bs[128 * 64];
    const int tid = threadIdx.x;
    const int w = tid >> 6, lane = tid & 63;
    const int wm = w >> 1, wn = w & 1;
    const int lhi = lane >> 4, llo = lane & 15;

    int nblk = gridDim.x;
    int q = nblk >> 3, r = nblk & 7;
    int xcd = blockIdx.x & 7, lo = blockIdx.x >> 3;
    int wg = ((xcd < r) ? xcd * (q + 1) : r * (q + 1) + (xcd - r) * q) + lo;
    int mt = wg % MT, nt = wg / MT;
    const int row0 = mt * 128, col0 = nt * 128;

    // per-lane staging sources: lane i covers LDS bytes [i*16, i*16+16) of its
    // 1KB chunk = row (i>>3), slot (i&7). Slot s holds logical col-slot s^(row&7).
    const int lr8 = lane >> 3;
    const int cs = (lane & 7) ^ lr8;
    const ushort* pA[4];
    const ushort* pB[4];
    #pragma unroll
    for (int qq = 0; qq < 4; ++qq) {
        int seg = w + qq * 4;
        int ra = row0 + seg * 8 + lr8; if (ra > M - 1) ra = M - 1;
        int rb = col0 + seg * 8 + lr8; if (rb > N - 1) rb = N - 1;
        pA[qq] = A + (size_t)ra * lda + cs * 8;
        pB[qq] = B + (size_t)rb * ldb + cs * 8;
    }

    f32x4 acc[4][4] = {};

    for (int kk = 0; kk < Kp; kk += 64) {
        #pragma unroll
        for (int qq = 0; qq < 4; ++qq) {
            int seg = w + qq * 4;
            GLOAD_LDS16(pA[qq] + kk, (char*)As + (seg << 10));
            GLOAD_LDS16(pB[qq] + kk, (char*)Bs + (seg << 10));
        }
        __syncthreads();
        #pragma unroll
        for (int ks = 0; ks < 2; ++ks) {
            short8b af[4], bg[4];
            #pragma unroll
            for (int i = 0; i < 4; ++i) {
                int Ra = wm * 64 + i * 16 + llo;
                int ca = (ks * 4 + lhi) ^ (Ra & 7);
                af[i] = *(const short8b*)((const char*)As + Ra * 128 + (ca << 4));
                int Rb = wn * 64 + i * 16 + llo;
                int cb = (ks * 4 + lhi) ^ (Rb & 7);
                bg[i] = *(const short8b*)((const char*)Bs + Rb * 128 + (cb << 4));
            }
            #pragma unroll
            for (int i = 0; i < 4; ++i)
                #pragma unroll
                for (int j = 0; j < 4; ++j)
                    acc[i][j] = __builtin_amdgcn_mfma_f32_16x16x32_bf16(af[i], bg[j], acc[i][j], 0, 0, 0);
        }
        __syncthreads();
    }

    if (MODE == 0) {
        #pragma unroll
        for (int i = 0; i < 4; ++i) {
            #pragma unroll
            for (int reg = 0; reg < 4; ++reg) {
                int row = row0 + wm * 64 + i * 16 + lhi * 4 + reg;
                if (row >= M) continue;
                #pragma unroll
                for (int j = 0; j < 4; ++j) {
                    int col = col0 + wn * 64 + j * 16 + llo;
                    if (col < N)
                        C[(size_t)row * ldc + col] = acc[i][j][reg] + (bias ? bias[col] : 0.f);
                }
            }
        }
    } else {
        #pragma unroll
        for (int i = 0; i < 4; ++i) {
            #pragma unroll
            for (int reg = 0; reg < 4; ++reg) {
                int row = row0 + wm * 64 + i * 16 + lhi * 4 + reg;
                float vals[4], vmax = -1e30f;
                #pragma unroll
                for (int j = 0; j < 4; ++j) {
                    int col = col0 + wn * 64 + j * 16 + llo;
                    vals[j] = (col < N) ? (acc[i][j][reg] + bias[col]) : -1e30f;
                    vmax = fmaxf(vmax, vals[j]);
                }
                #pragma unroll
                for (int off = 8; off; off >>= 1) vmax = fmaxf(vmax, __shfl_xor(vmax, off, 16));
                float se = 0.f;
                #pragma unroll
                for (int j = 0; j < 4; ++j) {
                    int col = col0 + wn * 64 + j * 16 + llo;
                    if (col < N) se += __expf(vals[j] - vmax);
                }
                #pragma unroll
                for (int off = 8; off; off >>= 1) se += __shfl_xor(se, off, 16);
                if (llo == 0 && row < M) {
                    pm[(size_t)row * NST + nt * 2 + wn] = vmax;
                    ps[(size_t)row * NST + nt * 2 + wn] = se;
                }
            }
        }
    }
}

// ---------------- LSTM step: enc+dec batched, 8 waves, split-K MFMA ---------
// grid (63, 2): y=0 encoder, y=1 decoder. Block: 16 hidden cols, 512 threads.
// wave = half*4 + gate; each wave: G_half = h(bf16) @ Whh[gate rows]^T over
// K-half via 16x16x32 MFMA, depth-4 pipelined loads. LDS exchange fuses update.
__global__ __launch_bounds__(512) void lstm_step8(
    const float* __restrict__ xpE, const float* __restrict__ xpD,
    const ushort* __restrict__ WE, const ushort* __restrict__ WD,
    float* __restrict__ cE, float* __restrict__ cD,
    ushort* __restrict__ hE, ushort* __restrict__ hD,
    int strideE, int strideD, int t)
{
    __shared__ float gsm[8][32][16];
    const int which = blockIdx.y;
    const float* xp = which ? xpD : xpE;
    const ushort* Whh = which ? WD : WE;
    float* cb = which ? cD : cE;
    ushort* hs = which ? hD : hE;
    const int hstride = which ? strideD : strideE;

    const int tid = threadIdx.x;
    const int wave = tid >> 6, l = tid & 63;
    const int g = wave & 3, half = wave >> 2;
    const int lhi = l >> 4, llo = l & 15;
    const int j0 = blockIdx.x * 16;
    const int jc = (j0 + llo < Hh) ? (j0 + llo) : (Hh - 1);
    const int kbase = half * 512;

    f32x4 acc0 = {0.f, 0.f, 0.f, 0.f};
    f32x4 acc1 = {0.f, 0.f, 0.f, 0.f};

    if (t > 0) {
        const ushort* wp  = Whh + (size_t)(g * Hh + jc) * 1024 + kbase + lhi * 8;
        const ushort* h0p = hs + ((size_t)llo * Tt + (t - 1)) * hstride + kbase + lhi * 8;
        const ushort* h1p = hs + ((size_t)(llo + 16) * Tt + (t - 1)) * hstride + kbase + lhi * 8;
        short8b wreg[4], a0r[4], a1r[4];
        #pragma unroll
        for (int pp = 0; pp < 4; ++pp) {
            wreg[pp] = *(const short8b*)(wp  + pp * 32);
            a0r[pp]  = *(const short8b*)(h0p + pp * 32);
            a1r[pp]  = *(const short8b*)(h1p + pp * 32);
        }
        #pragma unroll
        for (int kk = 0; kk < 16; ++kk) {
            short8b wc = wreg[kk & 3], a0 = a0r[kk & 3], a1 = a1r[kk & 3];
            if (kk + 4 < 16) {
                wreg[kk & 3] = *(const short8b*)(wp  + (kk + 4) * 32);
                a0r[kk & 3]  = *(const short8b*)(h0p + (kk + 4) * 32);
                a1r[kk & 3]  = *(const short8b*)(h1p + (kk + 4) * 32);
            }
            acc0 = __builtin_amdgcn_mfma_f32_16x16x32_bf16(a0, wc, acc0, 0, 0, 0);
            acc1 = __builtin_amdgcn_mfma_f32_16x16x32_bf16(a1, wc, acc1, 0, 0, 0);
        }
    }
    #pragma unroll
    for (int reg = 0; reg < 4; ++reg) {
        gsm[wave][lhi * 4 + reg][llo]      = acc0[reg];
        gsm[wave][16 + lhi * 4 + reg][llo] = acc1[reg];
    }
    __syncthreads();

    {
        int b = tid >> 4, jj = tid & 15;       // 512 threads = 32 batches x 16 cols
        int jw = j0 + jj;
        if (jw < Hh) {
            const float* xpr = xp + ((size_t)b * Tt + t) * Gg;
            float vi = gsm[0][b][jj] + gsm[4][b][jj] + xpr[jw];
            float vf = gsm[1][b][jj] + gsm[5][b][jj] + xpr[Hh + jw];
            float vg = gsm[2][b][jj] + gsm[6][b][jj] + xpr[2 * Hh + jw];
            float vo = gsm[3][b][jj] + gsm[7][b][jj] + xpr[3 * Hh + jw];
            float co = cb[(size_t)b * Hh + jw];
            float cn = sigf(vf) * co + sigf(vi) * tanhf(vg);
            float hn = sigf(vo) * tanhf(cn);
            cb[(size_t)b * Hh + jw] = cn;
            hs[((size_t)b * Tt + t) * hstride + jw] = f2bf(hn);
        }
    }
}

// ---------------- attention scores: one wave per (b,s,t) --------------------
__global__ __launch_bounds__(256) void attn_scores(
    const float* __restrict__ Ua, const float* __restrict__ Wa,
    const float* __restrict__ Va_w, const float* __restrict__ Va_b,
    float* __restrict__ scores)
{
    int wave = (blockIdx.x * 256 + threadIdx.x) >> 6;
    int lane = threadIdx.x & 63;
    if (wave >= Bb * Ss * Tt) return;
    int b = wave / (Ss * Tt);
    int rem = wave % (Ss * Tt);
    int s = rem / Tt, t = rem % Tt;
    const float* ua = Ua + (size_t)(b * Ss + s) * Hh;
    const float* wa = Wa + (size_t)(b * Tt + t) * Hh;
    float acc = 0.f;
    for (int h = lane; h < Hh; h += 64)
        acc += tanhf(ua[h] + wa[h]) * Va_w[h];
    #pragma unroll
    for (int off = 32; off; off >>= 1) acc += __shfl_xor(acc, off, 64);
    if (lane == 0) scores[(size_t)(b * Ss + s) * Tt + t] = acc + Va_b[0];
}

// ---------------- softmax over s + context (bf16 in, bf16 out into A_cat) --
__global__ __launch_bounds__(256) void softmax_context(
    const float* __restrict__ scores, const ushort* __restrict__ enc_hb,
    ushort* __restrict__ ctx_out, int ostride)
{
    __shared__ float w[Ss];
    int b = blockIdx.x / Tt, t = blockIdx.x % Tt;
    if (threadIdx.x == 0) {
        float sc[Ss];
        float mx = -1e30f;
        for (int s = 0; s < Ss; ++s) {
            sc[s] = scores[(size_t)(b * Ss + s) * Tt + t];
            mx = fmaxf(mx, sc[s]);
        }
        float sum = 0.f;
        for (int s = 0; s < Ss; ++s) { float e = __expf(sc[s] - mx); w[s] = e; sum += e; }
        float inv = 1.f / sum;
        for (int s = 0; s < Ss; ++s) w[s] *= inv;
    }
    __syncthreads();
    for (int h = threadIdx.x; h < Hh; h += 256) {
        float acc = 0.f;
        #pragma unroll
        for (int s = 0; s < Ss; ++s)
            acc += w[s] * bf2f(enc_hb[((size_t)b * Ss + s) * 1024 + h]);
        ctx_out[(size_t)(b * Tt + t) * ostride + h] = f2bf(acc);
    }
}

// ---------------- maxout: u[640][2000] -> tmax fp32 + tmax_b bf16 padded ---
__global__ void maxout(const float* __restrict__ u, float* __restrict__ tmax,
                       ushort* __restrict__ tmax_b) {
    int i = blockIdx.x * blockDim.x + threadIdx.x;   // over 640*1024
    if (i >= Bb * Tt * 1024) return;
    int row = i >> 10, m = i & 1023;
    ushort tb = 0;
    if (m < Mm) {
        float v = fmaxf(u[(size_t)row * 2 * Mm + 2 * m], u[(size_t)row * 2 * Mm + 2 * m + 1]);
        tmax[(size_t)row * Mm + m] = v;
        tb = f2bf(v);
    }
    tmax_b[(size_t)row * 1024 + m] = tb;
}

// ---------------- per-row NLL from logsumexp partials ----------------------
__global__ __launch_bounds__(256) void nll_kernel(
    const float* __restrict__ pm, const float* __restrict__ ps,
    const float* __restrict__ tmax, const float* __restrict__ Ww,
    const float* __restrict__ Wb, const int* __restrict__ y,
    float* __restrict__ nll)
{
    __shared__ float sm[4];
    int row = blockIdx.x;
    int tid = threadIdx.x;
    float mx = -1e30f;
    for (int i = tid; i < NST; i += 256) mx = fmaxf(mx, pm[(size_t)row * NST + i]);
    #pragma unroll
    for (int off = 32; off; off >>= 1) mx = fmaxf(mx, __shfl_xor(mx, off, 64));
    if ((tid & 63) == 0) sm[tid >> 6] = mx;
    __syncthreads();
    mx = fmaxf(fmaxf(sm[0], sm[1]), fmaxf(sm[2], sm[3]));
    __syncthreads();
    float s = 0.f;
    for (int i = tid; i < NST; i += 256)
        s += ps[(size_t)row * NST + i] * __expf(pm[(size_t)row * NST + i] - mx);
    #pragma unroll
    for (int off = 32; off; off >>= 1) s += __shfl_xor(s, off, 64);
    if ((tid & 63) == 0) sm[tid >> 6] = s;
    __syncthreads();
    s = sm[0] + sm[1] + sm[2] + sm[3];
    __syncthreads();
    int b = row / Tt, t = row % Tt;
    int lab = y[b * (Tt + 1) + t + 1];
    float d = 0.f;
    for (int m = tid; m < Mm; m += 256)
        d += tmax[(size_t)row * Mm + m] * Ww[(size_t)lab * Mm + m];
    #pragma unroll
    for (int off = 32; off; off >>= 1) d += __shfl_xor(d, off, 64);
    if ((tid & 63) == 0) sm[tid >> 6] = d;
    __syncthreads();
    d = sm[0] + sm[1] + sm[2] + sm[3] + Wb[lab];
    if (tid == 0) nll[row] = (mx + logf(s)) - d;
}

__global__ void loss_kernel(const float* __restrict__ nll, float* __restrict__ out) {
    __shared__ float sm[4];
    float s = 0.f;
    for (int i = threadIdx.x; i < Bb * Tt; i += 256) s += nll[i];
    #pragma unroll
    for (int off = 32; off; off >>= 1) s += __shfl_xor(s, off, 64);
    if ((threadIdx.x & 63) == 0) sm[threadIdx.x >> 6] = s;
    __syncthreads();
    if (threadIdx.x == 0) out[0] = (sm[0] + sm[1] + sm[2] + sm[3]) / (float)Bb;
}

extern "C" void kernel_launch(void* const* d_in, const int* in_sizes, int n_in,
                              void* d_out, int out_size, void* d_ws, size_t ws_size,
                              hipStream_t stream)
{
    const int* x = (const int*)d_in[0];
    const int* y = (const int*)d_in[1];
    const float* emb_de  = (const float*)d_in[2];
    const float* emb_en  = (const float*)d_in[3];
    const float* enc_Wih = (const float*)d_in[4];
    const float* enc_Whh = (const float*)d_in[5];
    const float* enc_b   = (const float*)d_in[6];
    const float* dec_Wih = (const float*)d_in[7];
    const float* dec_Whh = (const float*)d_in[8];
    const float* dec_b   = (const float*)d_in[9];
    const float* Wa_w = (const float*)d_in[10];
    const float* Wa_b = (const float*)d_in[11];
    const float* Ua_w = (const float*)d_in[12];
    const float* Ua_b = (const float*)d_in[13];
    const float* Va_w = (const float*)d_in[14];
    const float* Va_b = (const float*)d_in[15];
    const float* U_w  = (const float*)d_in[16];
    const float* U_b  = (const float*)d_in[17];
    const float* V_w  = (const float*)d_in[18];
    const float* V_b  = (const float*)d_in[19];
    const float* C_w  = (const float*)d_in[20];
    const float* C_b  = (const float*)d_in[21];
    const float* W_w  = (const float*)d_in[22];
    const float* W_b  = (const float*)d_in[23];

    char* base = (char*)d_ws;
    size_t off = 0;
    auto alloc = [&](size_t bytes) { char* p = base + off; off += (bytes + 255) & ~(size_t)255; return p; };

    float*  xp_enc   = (float*)alloc(640ull * 4000 * 4);   // alias: u, tmax
    float*  xp_dec   = (float*)alloc(640ull * 4000 * 4);   // alias: tmax_b
    float*  Wa       = (float*)alloc(640ull * 1000 * 4);
    float*  Ua       = (float*)alloc(640ull * 1000 * 4);
    float*  scores   = (float*)alloc((size_t)Bb * Ss * Tt * 4);
    float*  pm       = (float*)alloc(640ull * NST * 4);
    float*  ps       = (float*)alloc(640ull * NST * 4);
    float*  nll      = (float*)alloc(640ull * 4);
    float*  c_enc    = (float*)alloc(32ull * 1000 * 4);
    float*  c_dec    = (float*)alloc(32ull * 1000 * 4);
    float*  bias_cat = (float*)alloc(2000ull * 4);
    ushort* e_de_b   = (ushort*)alloc(640ull * 640 * 2);
    ushort* A_cat    = (ushort*)alloc(640ull * 2688 * 2);  // [dec_h 1024 | e_en 640 | ctx 1024]
    ushort* hs_enc_b = (ushort*)alloc(640ull * 1024 * 2);
    ushort* whh_enc_b= (ushort*)alloc(4000ull * 1024 * 2);
    ushort* whh_dec_b= (ushort*)alloc(4000ull * 1024 * 2);
    ushort* wbig     = (ushort*)alloc(30000ull * 1024 * 2); // W_w_b; wih bufs overlay (dead before W_w conv)
    ushort* Wcat_b   = (ushort*)alloc(2000ull * 2688 * 2);
    ushort* Wa_w_b   = (ushort*)alloc(1000ull * 1024 * 2);
    ushort* Ua_w_b   = (ushort*)alloc(1000ull * 1024 * 2);

    ushort* wih_enc_b = wbig;                               // 4000*640 each, dead after xp GEMMs
    ushort* wih_dec_b = wbig + 4000ull * 640;
    ushort* W_w_b     = wbig;

    float*  u      = xp_enc;                                // 640*2000 f32
    float*  tmax   = xp_enc + 640ull * 2000;                // 640*1000 f32
    ushort* tmax_b = (ushort*)xp_dec;                       // 640*1024 bf16

    dim3 blk(256);

    hipMemsetAsync(c_enc, 0, 2ull * 32 * 1000 * 4, stream);  // c_enc+c_dec contiguous
    hipMemsetAsync(hs_enc_b, 0, 640ull * 1024 * 2, stream);
    hipMemsetAsync(A_cat, 0, 640ull * 2688 * 2, stream);

    // ---- weight conversions (bf16, K padded to x64)
    conv_bf16<<<dim3(2000), blk, 0, stream>>>(enc_Whh, 1000, whh_enc_b, 1024, 1024, 4000 * 128);
    conv_bf16<<<dim3(2000), blk, 0, stream>>>(dec_Whh, 1000, whh_dec_b, 1024, 1024, 4000 * 128);
    conv_bf16<<<dim3(1250), blk, 0, stream>>>(enc_Wih, 620, wih_enc_b, 640, 640, 4000 * 80);
    conv_bf16<<<dim3(1250), blk, 0, stream>>>(dec_Wih, 620, wih_dec_b, 640, 640, 4000 * 80);
    conv_bf16<<<dim3(500),  blk, 0, stream>>>(Wa_w, 1000, Wa_w_b, 1024, 1024, 1000 * 128);
    conv_bf16<<<dim3(500),  blk, 0, stream>>>(Ua_w, 1000, Ua_w_b, 1024, 1024, 1000 * 128);
    conv_bf16<<<dim3(1000), blk, 0, stream>>>(U_w, 1000, Wcat_b,        2688, 1024, 2000 * 128);
    conv_bf16<<<dim3(625),  blk, 0, stream>>>(V_w,  620, Wcat_b + 1024, 2688,  640, 2000 * 80);
    conv_bf16<<<dim3(1000), blk, 0, stream>>>(C_w, 1000, Wcat_b + 1664, 2688, 1024, 2000 * 128);
    add3<<<dim3(8), blk, 0, stream>>>(U_b, V_b, C_b, bias_cat, 2000);

    // ---- embeddings -> bf16 (e_en straight into A_cat cols 1024..1663)
    gather_emb_bf16<<<dim3(200), blk, 0, stream>>>(emb_de, x, Ss, e_de_b, 640);
    gather_emb_bf16<<<dim3(200), blk, 0, stream>>>(emb_en, y, Tt + 1, A_cat + 1024, 2688);

    // ---- xp = e @ Wih^T + b   [640,4000], Kp=640
    gemm_nt<0><<<dim3(160), blk, 0, stream>>>(e_de_b, 640, wih_enc_b, 640, enc_b,
                                              xp_enc, 4000, nullptr, nullptr, 640, 4000, 640, 5);
    gemm_nt<0><<<dim3(160), blk, 0, stream>>>(A_cat + 1024, 2688, wih_dec_b, 640, dec_b,
                                              xp_dec, 4000, nullptr, nullptr, 640, 4000, 640, 5);

    // ---- W_w -> bf16 (overlays wih buffers; xp GEMMs above are done first)
    conv_bf16<<<dim3(15000), blk, 0, stream>>>(W_w, 1000, W_w_b, 1024, 1024, 30000 * 128);

    // ---- LSTM recurrences, enc+dec batched per step
    for (int t = 0; t < Tt; ++t)
        lstm_step8<<<dim3(63, 2), dim3(512), 0, stream>>>(
            xp_enc, xp_dec, whh_enc_b, whh_dec_b, c_enc, c_dec,
            hs_enc_b, A_cat, 1024, 2688, t);

    // ---- attention projections [640,1000], Kp=1024
    gemm_nt<0><<<dim3(40), blk, 0, stream>>>(A_cat, 2688, Wa_w_b, 1024, Wa_b,
                                             Wa, 1000, nullptr, nullptr, 640, 1000, 1024, 5);
    gemm_nt<0><<<dim3(40), blk, 0, stream>>>(hs_enc_b, 1024, Ua_w_b, 1024, Ua_b,
                                             Ua, 1000, nullptr, nullptr, 640, 1000, 1024, 5);

    attn_scores<<<dim3(3200), blk, 0, stream>>>(Ua, Wa, Va_w, Va_b, scores);
    softmax_context<<<dim3(640), blk, 0, stream>>>(scores, hs_enc_b, A_cat + 1664, 2688);

    // ---- u = A_cat @ Wcat^T + (U_b+V_b+C_b)   [640,2000], Kp=2688 (fused U,V,C)
    gemm_nt<0><<<dim3(80), blk, 0, stream>>>(A_cat, 2688, Wcat_b, 2688, bias_cat,
                                             u, 2000, nullptr, nullptr, 640, 2000, 2688, 5);

    maxout<<<dim3((640 * 1024 + 255) / 256), blk, 0, stream>>>(u, tmax, tmax_b);

    // ---- logits GEMM + fused logsumexp partials  [640,30000], Kp=1024
    gemm_nt<1><<<dim3(1175), blk, 0, stream>>>(tmax_b, 1024, W_w_b, 1024, W_b,
                                               nullptr, 0, pm, ps, 640, VEN_, 1024, 5);

    nll_kernel<<<dim3(640), blk, 0, stream>>>(pm, ps, tmax, W_w, W_b, y, nll);
    loss_kernel<<<dim3(1), blk, 0, stream>>>(nll, (float*)d_out);
}

// Round 5
// 604.126 us; speedup vs baseline: 11.5123x; 1.1583x over previous
//
#include <hip/hip_runtime.h>
#include <math.h>

#define VEN_  30000
#define Dd    620
#define Hh    1000
#define Gg    4000   // 4*H
#define Mm    1000
#define Bb    32
#define Ss    20
#define Tt    20
#define NST   470    // 2 * ceil(30000/128) stat slots per row

typedef __attribute__((ext_vector_type(8))) short short8b;  // 8 bf16
typedef __attribute__((ext_vector_type(4))) float f32x4;

typedef __attribute__((address_space(1))) void GASV;
typedef __attribute__((address_space(3))) void LASV;
#define GLOAD_LDS16(g, l) \
    __builtin_amdgcn_global_load_lds((GASV*)(const void*)(g), (LASV*)(void*)(l), 16, 0, 0)

__device__ __forceinline__ float sigf(float x) { return 1.0f / (1.0f + __expf(-x)); }
__device__ __forceinline__ ushort f2bf(float f) {            // RNE fp32->bf16
    unsigned u = __float_as_uint(f);
    u = (u + 0x7fffu + ((u >> 16) & 1u)) >> 16;
    return (ushort)u;
}
__device__ __forceinline__ float bf2f(ushort u) { return __uint_as_float(((unsigned)u) << 16); }
__device__ __forceinline__ short8b cvt8(float4 a, float4 b) {
    ushort v[8];
    v[0] = f2bf(a.x); v[1] = f2bf(a.y); v[2] = f2bf(a.z); v[3] = f2bf(a.w);
    v[4] = f2bf(b.x); v[5] = f2bf(b.y); v[6] = f2bf(b.z); v[7] = f2bf(b.w);
    return *(short8b*)v;
}

// ---------------- fp32 -> bf16 convert, vectorized, K-padded ---------------
__global__ void conv_bf16(const float* __restrict__ in, int K,
                          ushort* __restrict__ out, int ostride, int kp8, int total) {
    int idx = blockIdx.x * 256 + threadIdx.x;
    if (idx >= total) return;                 // total = R * kp8
    int rr = idx / kp8, c8 = (idx % kp8) * 8;
    const float* src = in + (size_t)rr * K + c8;
    short8b o;
    if (c8 + 7 < K) {
        o = cvt8(*(const float4*)src, *(const float4*)(src + 4));
    } else {
        ushort v[8];
        #pragma unroll
        for (int j = 0; j < 8; ++j) v[j] = (c8 + j < K) ? f2bf(src[j]) : (ushort)0;
        o = *(short8b*)v;
    }
    *(short8b*)&out[(size_t)rr * ostride + c8] = o;
}

// ---------------- merged multi-tensor convert (one dispatch) ---------------
struct ConvJob { const float* src; ushort* dst; int K; int ostride; int kp8; unsigned end; };
struct ConvJobs { ConvJob j[9]; };

__global__ void conv_multi(ConvJobs jobs, unsigned total) {
    unsigned v = blockIdx.x * 256 + threadIdx.x;
    if (v >= total) return;
    int ji = 0;
    while (v >= jobs.j[ji].end) ++ji;         // 9 jobs max, ends ascending
    unsigned base = ji ? jobs.j[ji - 1].end : 0;
    unsigned local = v - base;
    const ConvJob J = jobs.j[ji];
    int rr = local / J.kp8, c8 = (local % J.kp8) * 8;
    const float* src = J.src + (size_t)rr * J.K + c8;
    short8b o;
    if (c8 + 7 < J.K) {
        o = cvt8(*(const float4*)src, *(const float4*)(src + 4));
    } else {
        ushort w[8];
        #pragma unroll
        for (int j = 0; j < 8; ++j) w[j] = (c8 + j < J.K) ? f2bf(src[j]) : (ushort)0;
        o = *(short8b*)w;
    }
    *(short8b*)&J.dst[(size_t)rr * J.ostride + c8] = o;
}

__global__ void add3(const float* __restrict__ a, const float* __restrict__ b,
                     const float* __restrict__ c, float* __restrict__ o, int n) {
    int i = blockIdx.x * 256 + threadIdx.x;
    if (i < n) o[i] = a[i] + b[i] + c[i];
}

// ---------------- embedding gather -> bf16, K-padded ------------------------
__global__ void gather_emb_bf16(const float* __restrict__ emb, const int* __restrict__ toks,
                                int tstride, ushort* __restrict__ out, int ostride) {
    int idx = blockIdx.x * 256 + threadIdx.x;   // 640 * 80 chunks of 8
    if (idx >= Bb * Tt * 80) return;
    int row = idx / 80, c8 = (idx % 80) * 8;
    int b = row / Tt, t = row % Tt;
    int tok = toks[b * tstride + t];
    const float* src = emb + (size_t)tok * Dd + c8;
    short8b o;
    if (c8 + 7 < Dd) {
        o = cvt8(*(const float4*)src, *(const float4*)(src + 4));
    } else {
        ushort v[8];
        #pragma unroll
        for (int j = 0; j < 8; ++j) v[j] = (c8 + j < Dd) ? f2bf(src[j]) : (ushort)0;
        o = *(short8b*)v;
    }
    *(short8b*)&out[(size_t)row * ostride + c8] = o;
}

// ---------------- MFMA GEMM (m97 structure): C[M,N] = A[M,Kp] * B[N,Kp]^T ---
// Both operands bf16, K-padded to 64. 128x128 tile, 4 waves, BK=64,
// global_load_lds 16B direct staging with XOR slot swizzle (slot = c ^ (row&7))
// applied on the pre-swizzled GLOBAL source + swizzled ds_read (rule #21).
// Grid: 1D, bijective XCD swizzle (m204), col-panel-major for B-panel reuse.
// MODE 0: C = acc + bias. MODE 1: logsumexp partials. MODE 2: fused maxout
// (pair-max over adjacent cols -> tmax fp32 [M,1000] + tmax_b bf16 [M,1024]).
template <int MODE>
__global__ __launch_bounds__(256) void gemm_nt(
    const ushort* __restrict__ A, int lda,
    const ushort* __restrict__ B, int ldb,
    const float* __restrict__ bias,
    float* __restrict__ C, int ldc,
    float* __restrict__ pm, float* __restrict__ ps,
    ushort* __restrict__ Cb,
    int M, int N, int Kp, int MT)
{
    __shared__ __align__(16) ushort As[128 * 64];
    __shared__ __align__(16) ushort Bs[128 * 64];
    const int tid = threadIdx.x;
    const int w = tid >> 6, lane = tid & 63;
    const int wm = w >> 1, wn = w & 1;
    const int lhi = lane >> 4, llo = lane & 15;

    int nblk = gridDim.x;
    int q = nblk >> 3, r = nblk & 7;
    int xcd = blockIdx.x & 7, lo = blockIdx.x >> 3;
    int wg = ((xcd < r) ? xcd * (q + 1) : r * (q + 1) + (xcd - r) * q) + lo;
    int mt = wg % MT, nt = wg / MT;
    const int row0 = mt * 128, col0 = nt * 128;

    // per-lane staging sources: lane i covers LDS bytes [i*16, i*16+16) of its
    // 1KB chunk = row (i>>3), slot (i&7). Slot s holds logical col-slot s^(row&7).
    const int lr8 = lane >> 3;
    const int cs = (lane & 7) ^ lr8;
    const ushort* pA[4];
    const ushort* pB[4];
    #pragma unroll
    for (int qq = 0; qq < 4; ++qq) {
        int seg = w + qq * 4;
        int ra = row0 + seg * 8 + lr8; if (ra > M - 1) ra = M - 1;
        int rb = col0 + seg * 8 + lr8; if (rb > N - 1) rb = N - 1;
        pA[qq] = A + (size_t)ra * lda + cs * 8;
        pB[qq] = B + (size_t)rb * ldb + cs * 8;
    }

    f32x4 acc[4][4] = {};

    for (int kk = 0; kk < Kp; kk += 64) {
        #pragma unroll
        for (int qq = 0; qq < 4; ++qq) {
            int seg = w + qq * 4;
            GLOAD_LDS16(pA[qq] + kk, (char*)As + (seg << 10));
            GLOAD_LDS16(pB[qq] + kk, (char*)Bs + (seg << 10));
        }
        __syncthreads();
        #pragma unroll
        for (int ks = 0; ks < 2; ++ks) {
            short8b af[4], bg[4];
            #pragma unroll
            for (int i = 0; i < 4; ++i) {
                int Ra = wm * 64 + i * 16 + llo;
                int ca = (ks * 4 + lhi) ^ (Ra & 7);
                af[i] = *(const short8b*)((const char*)As + Ra * 128 + (ca << 4));
                int Rb = wn * 64 + i * 16 + llo;
                int cb = (ks * 4 + lhi) ^ (Rb & 7);
                bg[i] = *(const short8b*)((const char*)Bs + Rb * 128 + (cb << 4));
            }
            #pragma unroll
            for (int i = 0; i < 4; ++i)
                #pragma unroll
                for (int j = 0; j < 4; ++j)
                    acc[i][j] = __builtin_amdgcn_mfma_f32_16x16x32_bf16(af[i], bg[j], acc[i][j], 0, 0, 0);
        }
        __syncthreads();
    }

    if (MODE == 0) {
        #pragma unroll
        for (int i = 0; i < 4; ++i) {
            #pragma unroll
            for (int reg = 0; reg < 4; ++reg) {
                int row = row0 + wm * 64 + i * 16 + lhi * 4 + reg;
                if (row >= M) continue;
                #pragma unroll
                for (int j = 0; j < 4; ++j) {
                    int col = col0 + wn * 64 + j * 16 + llo;
                    if (col < N)
                        C[(size_t)row * ldc + col] = acc[i][j][reg] + (bias ? bias[col] : 0.f);
                }
            }
        }
    } else if (MODE == 1) {
        #pragma unroll
        for (int i = 0; i < 4; ++i) {
            #pragma unroll
            for (int reg = 0; reg < 4; ++reg) {
                int row = row0 + wm * 64 + i * 16 + lhi * 4 + reg;
                float vals[4], vmax = -1e30f;
                #pragma unroll
                for (int j = 0; j < 4; ++j) {
                    int col = col0 + wn * 64 + j * 16 + llo;
                    vals[j] = (col < N) ? (acc[i][j][reg] + bias[col]) : -1e30f;
                    vmax = fmaxf(vmax, vals[j]);
                }
                #pragma unroll
                for (int off = 8; off; off >>= 1) vmax = fmaxf(vmax, __shfl_xor(vmax, off, 16));
                float se = 0.f;
                #pragma unroll
                for (int j = 0; j < 4; ++j) {
                    int col = col0 + wn * 64 + j * 16 + llo;
                    if (col < N) se += __expf(vals[j] - vmax);
                }
                #pragma unroll
                for (int off = 8; off; off >>= 1) se += __shfl_xor(se, off, 16);
                if (llo == 0 && row < M) {
                    pm[(size_t)row * NST + nt * 2 + wn] = vmax;
                    ps[(size_t)row * NST + nt * 2 + wn] = se;
                }
            }
        }
    } else {   // MODE 2: fused maxout. C = tmax fp32 (ldc=1000), Cb = bf16 [*,1024]
        #pragma unroll
        for (int i = 0; i < 4; ++i) {
            #pragma unroll
            for (int reg = 0; reg < 4; ++reg) {
                int row = row0 + wm * 64 + i * 16 + lhi * 4 + reg;
                #pragma unroll
                for (int j = 0; j < 4; ++j) {
                    int col = col0 + wn * 64 + j * 16 + llo;
                    float v = acc[i][j][reg] + bias[col < N ? col : 0];
                    float o = fmaxf(v, __shfl_xor(v, 1));   // pair (2m, 2m+1)
                    if (((llo & 1) == 0) && row < M && col + 1 < N) {
                        int m = col >> 1;
                        C[(size_t)row * ldc + m] = o;
                        Cb[(size_t)row * 1024 + m] = f2bf(o);
                    }
                }
            }
        }
    }
}

// ---------------- LSTM step: enc+dec batched, 8 waves, split-K MFMA ---------
__global__ __launch_bounds__(512) void lstm_step8(
    const float* __restrict__ xpE, const float* __restrict__ xpD,
    const ushort* __restrict__ WE, const ushort* __restrict__ WD,
    float* __restrict__ cE, float* __restrict__ cD,
    ushort* __restrict__ hE, ushort* __restrict__ hD,
    int strideE, int strideD, int t)
{
    __shared__ float gsm[8][32][16];
    const int which = blockIdx.y;
    const float* xp = which ? xpD : xpE;
    const ushort* Whh = which ? WD : WE;
    float* cb = which ? cD : cE;
    ushort* hs = which ? hD : hE;
    const int hstride = which ? strideD : strideE;

    const int tid = threadIdx.x;
    const int wave = tid >> 6, l = tid & 63;
    const int g = wave & 3, half = wave >> 2;
    const int lhi = l >> 4, llo = l & 15;
    const int j0 = blockIdx.x * 16;
    const int jc = (j0 + llo < Hh) ? (j0 + llo) : (Hh - 1);
    const int kbase = half * 512;

    f32x4 acc0 = {0.f, 0.f, 0.f, 0.f};
    f32x4 acc1 = {0.f, 0.f, 0.f, 0.f};

    if (t > 0) {
        const ushort* wp  = Whh + (size_t)(g * Hh + jc) * 1024 + kbase + lhi * 8;
        const ushort* h0p = hs + ((size_t)llo * Tt + (t - 1)) * hstride + kbase + lhi * 8;
        const ushort* h1p = hs + ((size_t)(llo + 16) * Tt + (t - 1)) * hstride + kbase + lhi * 8;
        short8b wreg[4], a0r[4], a1r[4];
        #pragma unroll
        for (int pp = 0; pp < 4; ++pp) {
            wreg[pp] = *(const short8b*)(wp  + pp * 32);
            a0r[pp]  = *(const short8b*)(h0p + pp * 32);
            a1r[pp]  = *(const short8b*)(h1p + pp * 32);
        }
        #pragma unroll
        for (int kk = 0; kk < 16; ++kk) {
            short8b wc = wreg[kk & 3], a0 = a0r[kk & 3], a1 = a1r[kk & 3];
            if (kk + 4 < 16) {
                wreg[kk & 3] = *(const short8b*)(wp  + (kk + 4) * 32);
                a0r[kk & 3]  = *(const short8b*)(h0p + (kk + 4) * 32);
                a1r[kk & 3]  = *(const short8b*)(h1p + (kk + 4) * 32);
            }
            acc0 = __builtin_amdgcn_mfma_f32_16x16x32_bf16(a0, wc, acc0, 0, 0, 0);
            acc1 = __builtin_amdgcn_mfma_f32_16x16x32_bf16(a1, wc, acc1, 0, 0, 0);
        }
    }
    #pragma unroll
    for (int reg = 0; reg < 4; ++reg) {
        gsm[wave][lhi * 4 + reg][llo]      = acc0[reg];
        gsm[wave][16 + lhi * 4 + reg][llo] = acc1[reg];
    }
    __syncthreads();

    {
        int b = tid >> 4, jj = tid & 15;       // 512 threads = 32 batches x 16 cols
        int jw = j0 + jj;
        if (jw < Hh) {
            const float* xpr = xp + ((size_t)b * Tt + t) * Gg;
            float vi = gsm[0][b][jj] + gsm[4][b][jj] + xpr[jw];
            float vf = gsm[1][b][jj] + gsm[5][b][jj] + xpr[Hh + jw];
            float vg = gsm[2][b][jj] + gsm[6][b][jj] + xpr[2 * Hh + jw];
            float vo = gsm[3][b][jj] + gsm[7][b][jj] + xpr[3 * Hh + jw];
            float co = cb[(size_t)b * Hh + jw];
            float cn = sigf(vf) * co + sigf(vi) * tanhf(vg);
            float hn = sigf(vo) * tanhf(cn);
            cb[(size_t)b * Hh + jw] = cn;
            hs[((size_t)b * Tt + t) * hstride + jw] = f2bf(hn);
        }
    }
}

// ---------------- attention scores: one wave per (b,s,t) --------------------
__global__ __launch_bounds__(256) void attn_scores(
    const float* __restrict__ Ua, const float* __restrict__ Wa,
    const float* __restrict__ Va_w, const float* __restrict__ Va_b,
    float* __restrict__ scores)
{
    int wave = (blockIdx.x * 256 + threadIdx.x) >> 6;
    int lane = threadIdx.x & 63;
    if (wave >= Bb * Ss * Tt) return;
    int b = wave / (Ss * Tt);
    int rem = wave % (Ss * Tt);
    int s = rem / Tt, t = rem % Tt;
    const float* ua = Ua + (size_t)(b * Ss + s) * Hh;
    const float* wa = Wa + (size_t)(b * Tt + t) * Hh;
    float acc = 0.f;
    for (int h = lane; h < Hh; h += 64)
        acc += tanhf(ua[h] + wa[h]) * Va_w[h];
    #pragma unroll
    for (int off = 32; off; off >>= 1) acc += __shfl_xor(acc, off, 64);
    if (lane == 0) scores[(size_t)(b * Ss + s) * Tt + t] = acc + Va_b[0];
}

// ---------------- softmax over s + context (bf16 in, bf16 out into A_cat) --
__global__ __launch_bounds__(256) void softmax_context(
    const float* __restrict__ scores, const ushort* __restrict__ enc_hb,
    ushort* __restrict__ ctx_out, int ostride)
{
    __shared__ float w[Ss];
    int b = blockIdx.x / Tt, t = blockIdx.x % Tt;
    if (threadIdx.x == 0) {
        float sc[Ss];
        float mx = -1e30f;
        for (int s = 0; s < Ss; ++s) {
            sc[s] = scores[(size_t)(b * Ss + s) * Tt + t];
            mx = fmaxf(mx, sc[s]);
        }
        float sum = 0.f;
        for (int s = 0; s < Ss; ++s) { float e = __expf(sc[s] - mx); w[s] = e; sum += e; }
        float inv = 1.f / sum;
        for (int s = 0; s < Ss; ++s) w[s] *= inv;
    }
    __syncthreads();
    for (int h = threadIdx.x; h < Hh; h += 256) {
        float acc = 0.f;
        #pragma unroll
        for (int s = 0; s < Ss; ++s)
            acc += w[s] * bf2f(enc_hb[((size_t)b * Ss + s) * 1024 + h]);
        ctx_out[(size_t)(b * Tt + t) * ostride + h] = f2bf(acc);
    }
}

// ---------------- per-row NLL from logsumexp partials ----------------------
__global__ __launch_bounds__(256) void nll_kernel(
    const float* __restrict__ pm, const float* __restrict__ ps,
    const float* __restrict__ tmax, const float* __restrict__ Ww,
    const float* __restrict__ Wb, const int* __restrict__ y,
    float* __restrict__ nll)
{
    __shared__ float sm[4];
    int row = blockIdx.x;
    int tid = threadIdx.x;
    float mx = -1e30f;
    for (int i = tid; i < NST; i += 256) mx = fmaxf(mx, pm[(size_t)row * NST + i]);
    #pragma unroll
    for (int off = 32; off; off >>= 1) mx = fmaxf(mx, __shfl_xor(mx, off, 64));
    if ((tid & 63) == 0) sm[tid >> 6] = mx;
    __syncthreads();
    mx = fmaxf(fmaxf(sm[0], sm[1]), fmaxf(sm[2], sm[3]));
    __syncthreads();
    float s = 0.f;
    for (int i = tid; i < NST; i += 256)
        s += ps[(size_t)row * NST + i] * __expf(pm[(size_t)row * NST + i] - mx);
    #pragma unroll
    for (int off = 32; off; off >>= 1) s += __shfl_xor(s, off, 64);
    if ((tid & 63) == 0) sm[tid >> 6] = s;
    __syncthreads();
    s = sm[0] + sm[1] + sm[2] + sm[3];
    __syncthreads();
    int b = row / Tt, t = row % Tt;
    int lab = y[b * (Tt + 1) + t + 1];
    float d = 0.f;
    for (int m = tid; m < Mm; m += 256)
        d += tmax[(size_t)row * Mm + m] * Ww[(size_t)lab * Mm + m];
    #pragma unroll
    for (int off = 32; off; off >>= 1) d += __shfl_xor(d, off, 64);
    if ((tid & 63) == 0) sm[tid >> 6] = d;
    __syncthreads();
    d = sm[0] + sm[1] + sm[2] + sm[3] + Wb[lab];
    if (tid == 0) nll[row] = (mx + logf(s)) - d;
}

__global__ void loss_kernel(const float* __restrict__ nll, float* __restrict__ out) {
    __shared__ float sm[4];
    float s = 0.f;
    for (int i = threadIdx.x; i < Bb * Tt; i += 256) s += nll[i];
    #pragma unroll
    for (int off = 32; off; off >>= 1) s += __shfl_xor(s, off, 64);
    if ((threadIdx.x & 63) == 0) sm[threadIdx.x >> 6] = s;
    __syncthreads();
    if (threadIdx.x == 0) out[0] = (sm[0] + sm[1] + sm[2] + sm[3]) / (float)Bb;
}

extern "C" void kernel_launch(void* const* d_in, const int* in_sizes, int n_in,
                              void* d_out, int out_size, void* d_ws, size_t ws_size,
                              hipStream_t stream)
{
    const int* x = (const int*)d_in[0];
    const int* y = (const int*)d_in[1];
    const float* emb_de  = (const float*)d_in[2];
    const float* emb_en  = (const float*)d_in[3];
    const float* enc_Wih = (const float*)d_in[4];
    const float* enc_Whh = (const float*)d_in[5];
    const float* enc_b   = (const float*)d_in[6];
    const float* dec_Wih = (const float*)d_in[7];
    const float* dec_Whh = (const float*)d_in[8];
    const float* dec_b   = (const float*)d_in[9];
    const float* Wa_w = (const float*)d_in[10];
    const float* Wa_b = (const float*)d_in[11];
    const float* Ua_w = (const float*)d_in[12];
    const float* Ua_b = (const float*)d_in[13];
    const float* Va_w = (const float*)d_in[14];
    const float* Va_b = (const float*)d_in[15];
    const float* U_w  = (const float*)d_in[16];
    const float* U_b  = (const float*)d_in[17];
    const float* V_w  = (const float*)d_in[18];
    const float* V_b  = (const float*)d_in[19];
    const float* C_w  = (const float*)d_in[20];
    const float* C_b  = (const float*)d_in[21];
    const float* W_w  = (const float*)d_in[22];
    const float* W_b  = (const float*)d_in[23];

    char* base = (char*)d_ws;
    size_t off = 0;
    auto alloc = [&](size_t bytes) { char* p = base + off; off += (bytes + 255) & ~(size_t)255; return p; };

    float*  xp_enc   = (float*)alloc(640ull * 4000 * 4);   // alias: tmax
    float*  xp_dec   = (float*)alloc(640ull * 4000 * 4);   // alias: tmax_b
    float*  Wa       = (float*)alloc(640ull * 1000 * 4);
    float*  Ua       = (float*)alloc(640ull * 1000 * 4);
    float*  scores   = (float*)alloc((size_t)Bb * Ss * Tt * 4);
    float*  pm       = (float*)alloc(640ull * NST * 4);
    float*  ps       = (float*)alloc(640ull * NST * 4);
    float*  nll      = (float*)alloc(640ull * 4);
    float*  c_enc    = (float*)alloc(32ull * 1000 * 4);
    float*  c_dec    = (float*)alloc(32ull * 1000 * 4);
    float*  bias_cat = (float*)alloc(2000ull * 4);
    ushort* e_de_b   = (ushort*)alloc(640ull * 640 * 2);
    ushort* A_cat    = (ushort*)alloc(640ull * 2688 * 2);  // [dec_h 1024 | e_en 640 | ctx 1024]
    ushort* hs_enc_b = (ushort*)alloc(640ull * 1024 * 2);
    ushort* whh_enc_b= (ushort*)alloc(4000ull * 1024 * 2);
    ushort* whh_dec_b= (ushort*)alloc(4000ull * 1024 * 2);
    ushort* wbig     = (ushort*)alloc(30000ull * 1024 * 2); // W_w_b; wih bufs overlay (dead before W_w conv)
    ushort* Wcat_b   = (ushort*)alloc(2000ull * 2688 * 2);
    ushort* Wa_w_b   = (ushort*)alloc(1000ull * 1024 * 2);
    ushort* Ua_w_b   = (ushort*)alloc(1000ull * 1024 * 2);

    ushort* wih_enc_b = wbig;                               // 4000*640 each, dead after xp GEMMs
    ushort* wih_dec_b = wbig + 4000ull * 640;
    ushort* W_w_b     = wbig;

    float*  tmax   = xp_enc + 640ull * 2000;                // 640*1000 f32
    ushort* tmax_b = (ushort*)xp_dec;                       // 640*1024 bf16

    dim3 blk(256);

    hipMemsetAsync(c_enc, 0, 2ull * 32 * 1000 * 4, stream);  // c_enc+c_dec contiguous
    hipMemsetAsync(hs_enc_b, 0, 640ull * 1024 * 2, stream);
    hipMemsetAsync(A_cat, 0, 640ull * 2688 * 2, stream);

    // ---- all small weight conversions in ONE dispatch
    ConvJobs jobs;
    unsigned acc = 0;
    auto J = [&](int i, const float* s, ushort* d, int K, int ostr, int kp8, int R) {
        acc += (unsigned)R * kp8;
        jobs.j[i] = ConvJob{s, d, K, ostr, kp8, acc};
    };
    J(0, enc_Whh, whh_enc_b, 1000, 1024, 128, 4000);
    J(1, dec_Whh, whh_dec_b, 1000, 1024, 128, 4000);
    J(2, enc_Wih, wih_enc_b,  620,  640,  80, 4000);
    J(3, dec_Wih, wih_dec_b,  620,  640,  80, 4000);
    J(4, Wa_w,    Wa_w_b,    1000, 1024, 128, 1000);
    J(5, Ua_w,    Ua_w_b,    1000, 1024, 128, 1000);
    J(6, U_w,     Wcat_b,          1000, 2688, 128, 2000);
    J(7, V_w,     Wcat_b + 1024,    620, 2688,  80, 2000);
    J(8, C_w,     Wcat_b + 1664,   1000, 2688, 128, 2000);
    conv_multi<<<dim3((acc + 255) / 256), blk, 0, stream>>>(jobs, acc);
    add3<<<dim3(8), blk, 0, stream>>>(U_b, V_b, C_b, bias_cat, 2000);

    // ---- embeddings -> bf16 (e_en straight into A_cat cols 1024..1663)
    gather_emb_bf16<<<dim3(200), blk, 0, stream>>>(emb_de, x, Ss, e_de_b, 640);
    gather_emb_bf16<<<dim3(200), blk, 0, stream>>>(emb_en, y, Tt + 1, A_cat + 1024, 2688);

    // ---- xp = e @ Wih^T + b   [640,4000], Kp=640
    gemm_nt<0><<<dim3(160), blk, 0, stream>>>(e_de_b, 640, wih_enc_b, 640, enc_b,
                                              xp_enc, 4000, nullptr, nullptr, nullptr, 640, 4000, 640, 5);
    gemm_nt<0><<<dim3(160), blk, 0, stream>>>(A_cat + 1024, 2688, wih_dec_b, 640, dec_b,
                                              xp_dec, 4000, nullptr, nullptr, nullptr, 640, 4000, 640, 5);

    // ---- W_w -> bf16 (overlays wih buffers; xp GEMMs above are done first)
    conv_bf16<<<dim3(15000), blk, 0, stream>>>(W_w, 1000, W_w_b, 1024, 128, 30000 * 128);

    // ---- LSTM recurrences, enc+dec batched per step
    for (int t = 0; t < Tt; ++t)
        lstm_step8<<<dim3(63, 2), dim3(512), 0, stream>>>(
            xp_enc, xp_dec, whh_enc_b, whh_dec_b, c_enc, c_dec,
            hs_enc_b, A_cat, 1024, 2688, t);

    // ---- attention projections [640,1000], Kp=1024
    gemm_nt<0><<<dim3(40), blk, 0, stream>>>(A_cat, 2688, Wa_w_b, 1024, Wa_b,
                                             Wa, 1000, nullptr, nullptr, nullptr, 640, 1000, 1024, 5);
    gemm_nt<0><<<dim3(40), blk, 0, stream>>>(hs_enc_b, 1024, Ua_w_b, 1024, Ua_b,
                                             Ua, 1000, nullptr, nullptr, nullptr, 640, 1000, 1024, 5);

    attn_scores<<<dim3(3200), blk, 0, stream>>>(Ua, Wa, Va_w, Va_b, scores);
    softmax_context<<<dim3(640), blk, 0, stream>>>(scores, hs_enc_b, A_cat + 1664, 2688);

    // ---- tmax_b pad cols must be zero (A-side garbage x zero B-pad is safe
    //      only if not NaN); xp_dec is dead after the last LSTM step.
    hipMemsetAsync(tmax_b, 0, 640ull * 1024 * 2, stream);

    // ---- u-GEMM with fused maxout: tmax = maxpair(A_cat @ Wcat^T + bias)
    gemm_nt<2><<<dim3(80), blk, 0, stream>>>(A_cat, 2688, Wcat_b, 2688, bias_cat,
                                             tmax, 1000, nullptr, nullptr, tmax_b,
                                             640, 2000, 2688, 5);

    // ---- logits GEMM + fused logsumexp partials  [640,30000], Kp=1024
    gemm_nt<1><<<dim3(1175), blk, 0, stream>>>(tmax_b, 1024, W_w_b, 1024, W_b,
                                               nullptr, 0, pm, ps, nullptr, 640, VEN_, 1024, 5);

    nll_kernel<<<dim3(640), blk, 0, stream>>>(pm, ps, tmax, W_w, W_b, y, nll);
    loss_kernel<<<dim3(1), blk, 0, stream>>>(nll, (float*)d_out);
}